// Round 16
// baseline (1105.379 us; speedup 1.0000x reference)
//
#include <hip/hip_runtime.h>
#include <hip/hip_bf16.h>
#include <math.h>

#define B_  8
#define S_  512
#define H_  768
#define NH_ 12
#define D_  64
#define I_  3072
#define NTOK (B_*S_)   // 4096
#define LDQ 2304       // fused qkv row stride

typedef __attribute__((ext_vector_type(8))) __bf16 bf16x8;
typedef __attribute__((ext_vector_type(8))) unsigned short ushort8;
typedef __attribute__((ext_vector_type(4))) unsigned short ushort4v;
typedef __attribute__((ext_vector_type(4))) float  f32x4;

__device__ __forceinline__ float gelu_exact(float x) {
    return 0.5f * x * (1.0f + erff(x * 0.70710678118654752440f));
}

__device__ __forceinline__ unsigned short f2bf(float x) {
    __hip_bfloat16 h = __float2bfloat16(x);
    return *reinterpret_cast<unsigned short*>(&h);
}

__device__ __forceinline__ float bf2f(unsigned short u) {
    unsigned int v = ((unsigned int)u) << 16;
    return *reinterpret_cast<float*>(&v);
}

__device__ __forceinline__ void gload16(const void* g, void* l) {
    __builtin_amdgcn_global_load_lds(
        (const __attribute__((address_space(1))) void*)g,
        (__attribute__((address_space(3))) void*)l,
        16, 0, 0);
}

#define SB0() __builtin_amdgcn_sched_barrier(0)

// -------------------- f32 [K][N] -> bf16 [N][K] transpose-convert --------------------
__global__ void cvtT_kernel(const float* __restrict__ W, __hip_bfloat16* __restrict__ WT,
                            int K, int N) {
    __shared__ float tile[32][33];
    int k0 = blockIdx.y * 32, n0 = blockIdx.x * 32;
    int tx = threadIdx.x & 31, ty = threadIdx.x >> 5;   // 32x8
    #pragma unroll
    for (int i = 0; i < 32; i += 8)
        tile[ty + i][tx] = W[(long)(k0 + ty + i) * N + n0 + tx];
    __syncthreads();
    #pragma unroll
    for (int i = 0; i < 32; i += 8)
        WT[(long)(n0 + ty + i) * K + k0 + tx] = __float2bfloat16(tile[tx][ty + i]);
}

// -------------------- bias concat (bq|bk|bv -> bqkv) --------------------
__global__ void bias_concat_kernel(const float* __restrict__ bq,
                                   const float* __restrict__ bk,
                                   const float* __restrict__ bv,
                                   float* __restrict__ bqkv) {
    int i = blockIdx.x * 256 + threadIdx.x;   // 0..2303
    const float* src = (i < H_) ? bq : (i < 2 * H_) ? bk : bv;
    bqkv[i] = src[i % H_];
}

// ============ LayerNorm family: 192 threads, float4 (16B/lane) ============
__device__ __forceinline__ void ln_finish(float e0, float e1, float e2, float e3,
                                          int tid, float* tot1, float* tot2) {
    float s1 = e0 + e1 + e2 + e3;
    float s2 = e0 * e0 + e1 * e1 + e2 * e2 + e3 * e3;
    #pragma unroll
    for (int o = 32; o > 0; o >>= 1) { s1 += __shfl_xor(s1, o); s2 += __shfl_xor(s2, o); }
    __shared__ float ws1[3], ws2[3];
    int wid = tid >> 6;
    if ((tid & 63) == 0) { ws1[wid] = s1; ws2[wid] = s2; }
    __syncthreads();
    *tot1 = ws1[0] + ws1[1] + ws1[2];
    *tot2 = ws2[0] + ws2[1] + ws2[2];
}

__device__ __forceinline__ void ln_store(f32x4 e, float mean, float inv,
                                         const float* __restrict__ g,
                                         const float* __restrict__ bb,
                                         float* __restrict__ out,
                                         __hip_bfloat16* __restrict__ outb,
                                         long t, int tid) {
    f32x4 gv = reinterpret_cast<const f32x4*>(g)[tid];
    f32x4 bv = reinterpret_cast<const f32x4*>(bb)[tid];
    f32x4 r;
    #pragma unroll
    for (int i = 0; i < 4; ++i) r[i] = (e[i] - mean) * inv * gv[i] + bv[i];
    reinterpret_cast<f32x4*>(out + t * H_)[tid] = r;
    ushort4v u;
    #pragma unroll
    for (int i = 0; i < 4; ++i) u[i] = f2bf(r[i]);
    reinterpret_cast<ushort4v*>(reinterpret_cast<unsigned short*>(outb) + t * H_)[tid] = u;
}

// embeddings + LN
__global__ void embed_ln_kernel(const int* __restrict__ ids,
                                const float* __restrict__ Wword,
                                const float* __restrict__ Wpos,
                                const float* __restrict__ Wtype,
                                const float* __restrict__ g,
                                const float* __restrict__ b,
                                float* __restrict__ out,
                                __hip_bfloat16* __restrict__ outb) {
    long t = blockIdx.x;
    int s = (int)(t % S_);
    long id = ids[t];
    int tid = threadIdx.x;   // 0..191
    f32x4 e = reinterpret_cast<const f32x4*>(Wword + id * H_)[tid];
    f32x4 p = reinterpret_cast<const f32x4*>(Wpos + (long)s * H_)[tid];
    f32x4 y = reinterpret_cast<const f32x4*>(Wtype)[tid];
    #pragma unroll
    for (int i = 0; i < 4; ++i) e[i] += p[i] + y[i];
    float tot1, tot2;
    ln_finish(e[0], e[1], e[2], e[3], tid, &tot1, &tot2);
    float mean = tot1 * (1.0f / H_);
    float var  = tot2 * (1.0f / H_) - mean * mean;
    ln_store(e, mean, rsqrtf(var + 1e-12f), g, b, out, outb, t, tid);
}

// LN(a + p0 + p1), partials in bf16
__global__ void add_ln3_kernel(const float* __restrict__ a,
                               const __hip_bfloat16* __restrict__ p0,
                               const __hip_bfloat16* __restrict__ p1,
                               const float* __restrict__ g,
                               const float* __restrict__ bb,
                               float* __restrict__ out,
                               __hip_bfloat16* __restrict__ outb) {
    long t = blockIdx.x;
    int tid = threadIdx.x;
    long idx = t * (H_ / 4) + tid;
    f32x4 e = reinterpret_cast<const f32x4*>(a)[idx];
    ushort4v u = reinterpret_cast<const ushort4v*>(p0)[idx];
    ushort4v v = reinterpret_cast<const ushort4v*>(p1)[idx];
    #pragma unroll
    for (int i = 0; i < 4; ++i) e[i] += bf2f(u[i]) + bf2f(v[i]);
    float tot1, tot2;
    ln_finish(e[0], e[1], e[2], e[3], tid, &tot1, &tot2);
    float mean = tot1 * (1.0f / H_);
    float var  = tot2 * (1.0f / H_) - mean * mean;
    ln_store(e, mean, rsqrtf(var + 1e-12f), g, bb, out, outb, t, tid);
}

// LN(a + p0 + p1 + p2 + p3), partials in bf16
__global__ void add_ln5_kernel(const float* __restrict__ a,
                               const __hip_bfloat16* __restrict__ p0,
                               const __hip_bfloat16* __restrict__ p1,
                               const __hip_bfloat16* __restrict__ p2,
                               const __hip_bfloat16* __restrict__ p3,
                               const float* __restrict__ g,
                               const float* __restrict__ bb,
                               float* __restrict__ out,
                               __hip_bfloat16* __restrict__ outb) {
    long t = blockIdx.x;
    int tid = threadIdx.x;
    long idx = t * (H_ / 4) + tid;
    f32x4 e  = reinterpret_cast<const f32x4*>(a)[idx];
    ushort4v u0 = reinterpret_cast<const ushort4v*>(p0)[idx];
    ushort4v u1 = reinterpret_cast<const ushort4v*>(p1)[idx];
    ushort4v u2 = reinterpret_cast<const ushort4v*>(p2)[idx];
    ushort4v u3 = reinterpret_cast<const ushort4v*>(p3)[idx];
    #pragma unroll
    for (int i = 0; i < 4; ++i)
        e[i] += (bf2f(u0[i]) + bf2f(u1[i])) + (bf2f(u2[i]) + bf2f(u3[i]));
    float tot1, tot2;
    ln_finish(e[0], e[1], e[2], e[3], tid, &tot1, &tot2);
    float mean = tot1 * (1.0f / H_);
    float var  = tot2 * (1.0f / H_) - mean * mean;
    ln_store(e, mean, rsqrtf(var + 1e-12f), g, bb, out, outb, t, tid);
}

// ============ bf16 MFMA GEMM: 128x64 tiles, 1-barrier pipelined loop (T3 minimum recipe) ============
// Per K-step: STAGE(next buf) -> ds_read(cur) -> MFMA -> vmcnt(0) -> barrier.
// DMA latency drains under the step's own ds_read+MFMA; ONE barrier per step.
// Race safety: readers of buf finish ds_reads before the step-end barrier (MFMA forces
// lgkmcnt); overwrite of buf is issued only after all waves pass that barrier;
// vmcnt(0)+barrier ensure next buf's DMA landed before step t+1 reads it.
// K-granule swizzle (HW-verified 0-conflict). Split-K via gridDim.z (partials per z-plane).
template<int BM, int BN, int MI, int NJ, int ACT, int WF32, int WB16>
__global__ __launch_bounds__(256, 6) void mfma_gemm_kernel(
    const __hip_bfloat16* __restrict__ A,
    const __hip_bfloat16* __restrict__ BT,
    const float* __restrict__ bias,
    float* __restrict__ Cf,
    __hip_bfloat16* __restrict__ Cb,
    int M, int N, int Kc, int lda, int ldb) {
    constexpr int WC = BN / (NJ * 16);
    constexpr int WR = BM / (MI * 16);
    static_assert(WR * WC == 4, "4 waves");
    constexpr int LA = BM * 4 / 256;
    constexpr int LB = BN * 4 / 256;
    __shared__ __align__(16) __hip_bfloat16 sA[2][BM * 32];
    __shared__ __align__(16) __hip_bfloat16 sB[2][BN * 32];
    const int tid  = threadIdx.x;
    const int lane = tid & 63;
    const int w    = tid >> 6;
    const int wr   = w / WC, wc = w % WC;
    const int l15  = lane & 15, l4 = lane >> 4;
    const int m0 = blockIdx.y * BM, n0 = blockIdx.x * BN;
    const int koff = blockIdx.z * Kc;
    const int goff = (l15 >> 1) & 3;

    auto stage = [&](int buf, int k0) {
        #pragma unroll
        for (int t = 0; t < LA; ++t) {
            int c = tid + 256 * t;
            int row = c >> 2, gq = c & 3;
            int gsrc = gq ^ ((row >> 1) & 3);
            gload16(A + (long)(m0 + row) * lda + koff + k0 + gsrc * 8, &sA[buf][row * 32 + gq * 8]);
        }
        #pragma unroll
        for (int t = 0; t < LB; ++t) {
            int c = tid + 256 * t;
            int row = c >> 2, gq = c & 3;
            int gsrc = gq ^ ((row >> 1) & 3);
            gload16(BT + (long)(n0 + row) * ldb + koff + k0 + gsrc * 8, &sB[buf][row * 32 + gq * 8]);
        }
    };

    f32x4 acc[MI][NJ] = {};
    const int nk = Kc >> 5;

    // prologue: tile 0 staged and visible
    stage(0, 0);
    asm volatile("s_waitcnt vmcnt(0)" ::: "memory");
    SB0(); __builtin_amdgcn_s_barrier(); SB0();

    for (int t = 0; t < nk; ++t) {
        const int cur = t & 1;
        const bool more = (t + 1 < nk);
        if (more) stage(cur ^ 1, (t + 1) * 32);   // DMA issues; drains under this step's compute

        const int gsw = (l4 ^ goff) * 8;
        bf16x8 af[MI], bf[NJ];
        #pragma unroll
        for (int i = 0; i < MI; ++i)
            af[i] = *reinterpret_cast<const bf16x8*>(&sA[cur][(wr * MI * 16 + i * 16 + l15) * 32 + gsw]);
        #pragma unroll
        for (int j = 0; j < NJ; ++j)
            bf[j] = *reinterpret_cast<const bf16x8*>(&sB[cur][(wc * NJ * 16 + j * 16 + l15) * 32 + gsw]);
        #pragma unroll
        for (int i = 0; i < MI; ++i)
            #pragma unroll
            for (int j = 0; j < NJ; ++j)
                acc[i][j] = __builtin_amdgcn_mfma_f32_16x16x32_bf16(af[i], bf[j], acc[i][j], 0, 0, 0);

        if (more) {
            SB0();
            asm volatile("s_waitcnt vmcnt(0)" ::: "memory");   // next buf's DMA landed
            SB0(); __builtin_amdgcn_s_barrier(); SB0();        // single barrier per step
        }
    }

    float*          Cfz = Cf + (size_t)blockIdx.z * M * N;
    __hip_bfloat16* Cbz = Cb + (size_t)blockIdx.z * M * N;
    const bool addb = (blockIdx.z == 0);
    #pragma unroll
    for (int i = 0; i < MI; ++i) {
        #pragma unroll
        for (int j = 0; j < NJ; ++j) {
            int col = n0 + wc * NJ * 16 + j * 16 + l15;
            float bv = addb ? bias[col] : 0.f;
            #pragma unroll
            for (int r = 0; r < 4; ++r) {
                int row = m0 + wr * MI * 16 + i * 16 + l4 * 4 + r;
                float v = acc[i][j][r] + bv;
                if (ACT == 1) v = gelu_exact(v);
                if (WF32) Cfz[(long)row * N + col] = v;
                if (WB16) Cbz[(long)row * N + col] = __float2bfloat16(v);
            }
        }
    }
}

// -------------------- fused flash attention on fused QKV buffer --------------------
__global__ __launch_bounds__(256, 4) void flash_attn_kernel(
    const __hip_bfloat16* __restrict__ QKV,
    __hip_bfloat16* __restrict__ Ctx) {
    __shared__ __align__(16) unsigned short sK[64 * 72];
    __shared__ __align__(16) unsigned short sVt[64 * 72];
    __shared__ __align__(16) unsigned short sP[4 * 16 * 72];

    const int tid  = threadIdx.x;
    const int lane = tid & 63;
    const int w    = tid >> 6;
    const int l15  = lane & 15, l4 = lane >> 4;
    const int qb = blockIdx.x;
    const int bh = blockIdx.y;
    const int b  = bh / NH_, hd = bh % NH_;
    const long rbase = (long)b * S_ * LDQ;
    const int qoff = hd * D_, koff = H_ + hd * D_, voff = 2 * H_ + hd * D_;

    const int qrow0 = qb * 64 + w * 16;
    bf16x8 af[2];
    #pragma unroll
    for (int ks = 0; ks < 2; ++ks)
        af[ks] = *reinterpret_cast<const bf16x8*>(
            QKV + rbase + (long)(qrow0 + l15) * LDQ + qoff + ks * 32 + l4 * 8);

    f32x4 ctx[4] = {};
    float m_run[4], l_run[4];
    #pragma unroll
    for (int r = 0; r < 4; ++r) { m_run[r] = -1e30f; l_run[r] = 0.f; }

    const int sr = tid >> 2;
    const int sc = (tid & 3) * 16;
    unsigned short* pl = sP + w * (16 * 72);

    for (int kv0 = 0; kv0 < S_; kv0 += 64) {
        const __hip_bfloat16* kg = QKV + rbase + (long)(kv0 + sr) * LDQ + koff + sc;
        const __hip_bfloat16* vg = QKV + rbase + (long)(kv0 + sr) * LDQ + voff + sc;
        ushort8 kv_a = *reinterpret_cast<const ushort8*>(kg);
        ushort8 kv_b = *reinterpret_cast<const ushort8*>(kg + 8);
        ushort8 vv_a = *reinterpret_cast<const ushort8*>(vg);
        ushort8 vv_b = *reinterpret_cast<const ushort8*>(vg + 8);
        __syncthreads();
        *reinterpret_cast<ushort8*>(sK + sr * 72 + sc)     = kv_a;
        *reinterpret_cast<ushort8*>(sK + sr * 72 + sc + 8) = kv_b;
        #pragma unroll
        for (int i = 0; i < 8; ++i) {
            sVt[(sc + i) * 72 + sr]     = vv_a[i];
            sVt[(sc + 8 + i) * 72 + sr] = vv_b[i];
        }
        __syncthreads();

        f32x4 s[4];
        __builtin_amdgcn_s_setprio(1);
        #pragma unroll
        for (int j = 0; j < 4; ++j) {
            s[j] = (f32x4){0.f, 0.f, 0.f, 0.f};
            #pragma unroll
            for (int ks = 0; ks < 2; ++ks) {
                bf16x8 bk = *reinterpret_cast<const bf16x8*>(sK + (j * 16 + l15) * 72 + ks * 32 + l4 * 8);
                s[j] = __builtin_amdgcn_mfma_f32_16x16x32_bf16(af[ks], bk, s[j], 0, 0, 0);
            }
        }
        __builtin_amdgcn_s_setprio(0);
        #pragma unroll
        for (int j = 0; j < 4; ++j) s[j] *= 0.125f;

        #pragma unroll
        for (int r = 0; r < 4; ++r) {
            float mx = fmaxf(fmaxf(s[0][r], s[1][r]), fmaxf(s[2][r], s[3][r]));
            #pragma unroll
            for (int o = 1; o < 16; o <<= 1) mx = fmaxf(mx, __shfl_xor(mx, o));
            float mnew = fmaxf(m_run[r], mx);
            float sum = 0.f;
            #pragma unroll
            for (int j = 0; j < 4; ++j) {
                float p = __expf(s[j][r] - mnew);
                s[j][r] = p; sum += p;
            }
            #pragma unroll
            for (int o = 1; o < 16; o <<= 1) sum += __shfl_xor(sum, o);
            float resc = __expf(m_run[r] - mnew);
            l_run[r] = l_run[r] * resc + sum;
            m_run[r] = mnew;
            #pragma unroll
            for (int j = 0; j < 4; ++j) ctx[j][r] *= resc;
        }

        #pragma unroll
        for (int j = 0; j < 4; ++j)
            #pragma unroll
            for (int r = 0; r < 4; ++r)
                pl[(l4 * 4 + r) * 72 + j * 16 + l15] = f2bf(s[j][r]);

        __builtin_amdgcn_s_setprio(1);
        #pragma unroll
        for (int ks = 0; ks < 2; ++ks) {
            bf16x8 ap = *reinterpret_cast<const bf16x8*>(pl + l15 * 72 + ks * 32 + l4 * 8);
            #pragma unroll
            for (int jd = 0; jd < 4; ++jd) {
                bf16x8 bv = *reinterpret_cast<const bf16x8*>(sVt + (jd * 16 + l15) * 72 + ks * 32 + l4 * 8);
                ctx[jd] = __builtin_amdgcn_mfma_f32_16x16x32_bf16(ap, bv, ctx[jd], 0, 0, 0);
            }
        }
        __builtin_amdgcn_s_setprio(0);
    }

    #pragma unroll
    for (int r = 0; r < 4; ++r) {
        float inv = 1.f / l_run[r];
        long tok = (long)b * S_ + qb * 64 + w * 16 + l4 * 4 + r;
        #pragma unroll
        for (int jd = 0; jd < 4; ++jd)
            Ctx[tok * H_ + hd * D_ + jd * 16 + l15] = __float2bfloat16(ctx[jd][r] * inv);
    }
}

// -------------------- pooled head v2: one wave per output column --------------------
__global__ void pooled2_kernel(const float* __restrict__ h,
                               const __hip_bfloat16* __restrict__ WpT,
                               const float* __restrict__ bp,
                               float* __restrict__ out) {
    const int col = blockIdx.x, b = blockIdx.y;
    const int lane = threadIdx.x;
    const float* hb = h + (long)b * S_ * H_;
    const __hip_bfloat16* wp = WpT + (long)col * H_;
    float acc = 0.f;
    #pragma unroll
    for (int i = 0; i < H_ / 64; ++i) {
        int k = lane + i * 64;
        acc += hb[k] * __bfloat162float(wp[k]);
    }
    #pragma unroll
    for (int o = 32; o > 0; o >>= 1) acc += __shfl_xor(acc, o);
    if (lane == 0) out[(long)b * H_ + col] = acc + bp[col];
}

extern "C" void kernel_launch(void* const* d_in, const int* in_sizes, int n_in,
                              void* d_out, int out_size, void* d_ws, size_t ws_size,
                              hipStream_t stream) {
    const int*   x      = (const int*)  d_in[0];
    const float* W_word = (const float*)d_in[1];
    const float* W_pos  = (const float*)d_in[2];
    const float* W_type = (const float*)d_in[3];
    const float* g_emb  = (const float*)d_in[4];
    const float* b_emb  = (const float*)d_in[5];
    const float* Wq     = (const float*)d_in[6];
    const float* bq     = (const float*)d_in[7];
    const float* Wk     = (const float*)d_in[8];
    const float* bk     = (const float*)d_in[9];
    const float* Wv     = (const float*)d_in[10];
    const float* bv     = (const float*)d_in[11];
    const float* Wo     = (const float*)d_in[12];
    const float* bo     = (const float*)d_in[13];
    const float* g_attn = (const float*)d_in[14];
    const float* b_attn = (const float*)d_in[15];
    const float* Wi     = (const float*)d_in[16];
    const float* bi     = (const float*)d_in[17];
    const float* Wd     = (const float*)d_in[18];
    const float* bd     = (const float*)d_in[19];
    const float* g_out  = (const float*)d_in[20];
    const float* b_out  = (const float*)d_in[21];
    const float* Wp     = (const float*)d_in[22];
    const float* bp     = (const float*)d_in[23];

    const size_t NT = (size_t)NTOK * H_;
    char* base = (char*)d_ws;
    size_t off = 0;
    auto alloc = [&](size_t bytes) -> char* {
        char* p = base + off;
        off += (bytes + 255) & ~(size_t)255;
        return p;
    };
    float* h    = (float*)alloc(NT * 4);
    float* xa   = (float*)alloc(NT * 4);
    __hip_bfloat16* kbb = (__hip_bfloat16*)alloc(NT * 2 * 4);   // bf16 split-K partials (4 planes)
    __hip_bfloat16* kbb1 = kbb + NT;
    __hip_bfloat16* kbb2 = kbb + 2 * NT;
    __hip_bfloat16* kbb3 = kbb + 3 * NT;
    __hip_bfloat16* h_b   = (__hip_bfloat16*)alloc(NT * 2);
    __hip_bfloat16* xa_b  = (__hip_bfloat16*)alloc(NT * 2);
    __hip_bfloat16* qkv_b = (__hip_bfloat16*)alloc((size_t)NTOK * LDQ * 2);
    __hip_bfloat16* ctx_b = (__hip_bfloat16*)alloc(NT * 2);
    __hip_bfloat16* ff1_b = (__hip_bfloat16*)alloc((size_t)NTOK * I_ * 2);
    __hip_bfloat16* WqkvT = (__hip_bfloat16*)alloc((size_t)LDQ * H_ * 2);
    __hip_bfloat16* WoT = (__hip_bfloat16*)alloc((size_t)H_ * H_ * 2);
    __hip_bfloat16* WiT = (__hip_bfloat16*)alloc((size_t)H_ * I_ * 2);
    __hip_bfloat16* WdT = (__hip_bfloat16*)alloc((size_t)I_ * H_ * 2);
    __hip_bfloat16* WpT = (__hip_bfloat16*)alloc((size_t)H_ * H_ * 2);
    float* bqkv = (float*)alloc(LDQ * 4);

    cvtT_kernel<<<dim3(H_/32, H_/32), 256, 0, stream>>>(Wq, WqkvT, H_, H_);
    cvtT_kernel<<<dim3(H_/32, H_/32), 256, 0, stream>>>(Wk, WqkvT + (size_t)H_ * H_, H_, H_);
    cvtT_kernel<<<dim3(H_/32, H_/32), 256, 0, stream>>>(Wv, WqkvT + (size_t)2 * H_ * H_, H_, H_);
    cvtT_kernel<<<dim3(H_/32, H_/32), 256, 0, stream>>>(Wo, WoT, H_, H_);
    cvtT_kernel<<<dim3(I_/32, H_/32), 256, 0, stream>>>(Wi, WiT, H_, I_);
    cvtT_kernel<<<dim3(H_/32, I_/32), 256, 0, stream>>>(Wd, WdT, I_, H_);
    cvtT_kernel<<<dim3(H_/32, H_/32), 256, 0, stream>>>(Wp, WpT, H_, H_);
    bias_concat_kernel<<<LDQ/256, 256, 0, stream>>>(bq, bk, bv, bqkv);

    embed_ln_kernel<<<NTOK, 192, 0, stream>>>(x, W_word, W_pos, W_type, g_emb, b_emb, h, h_b);

    float* hout = (float*)d_out;   // last layer writes d_out directly
    dim3 gqkv(LDQ/64, NTOK/128);         // (36, 32) = 1152 blocks
    dim3 gi(I_/64, NTOK/128);            // (48, 32) = 1536 blocks
    dim3 go(H_/64, NTOK/128, 2);         // (12, 32, 2) = 768 blocks, split-K=2
    dim3 gff2(H_/64, NTOK/128, 4);       // (12, 32, 4) = 1536 blocks, split-K=4
    for (int layer = 0; layer < 6; ++layer) {
        mfma_gemm_kernel<128,64,4,2,0,0,1><<<gqkv, 256, 0, stream>>>(
            h_b, WqkvT, bqkv, nullptr, qkv_b, NTOK, LDQ, H_, H_, H_);
        flash_attn_kernel<<<dim3(S_/64, B_*NH_), 256, 0, stream>>>(qkv_b, ctx_b);
        mfma_gemm_kernel<128,64,4,2,0,0,1><<<go, 256, 0, stream>>>(
            ctx_b, WoT, bo, nullptr, kbb, NTOK, H_, H_/2, H_, H_);
        add_ln3_kernel<<<NTOK, 192, 0, stream>>>(h, kbb, kbb1, g_attn, b_attn, xa, xa_b);
        mfma_gemm_kernel<128,64,4,2,1,0,1><<<gi, 256, 0, stream>>>(
            xa_b, WiT, bi, nullptr, ff1_b, NTOK, I_, H_, H_, H_);
        mfma_gemm_kernel<128,64,4,2,0,0,1><<<gff2, 256, 0, stream>>>(
            ff1_b, WdT, bd, nullptr, kbb, NTOK, H_, I_/4, I_, I_);
        float* dst = (layer == 5) ? hout : h;
        add_ln5_kernel<<<NTOK, 192, 0, stream>>>(xa, kbb, kbb1, kbb2, kbb3,
                                                 g_out, b_out, dst, h_b);
    }

    pooled2_kernel<<<dim3(H_, B_), 64, 0, stream>>>(hout, WpT, bp, (float*)d_out + NT);
}

// Round 17
// 1073.577 us; speedup vs baseline: 1.0296x; 1.0296x over previous
//
#include <hip/hip_runtime.h>
#include <hip/hip_bf16.h>
#include <math.h>

#define B_  8
#define S_  512
#define H_  768
#define NH_ 12
#define D_  64
#define I_  3072
#define NTOK (B_*S_)   // 4096
#define LDQ 2304       // fused qkv row stride

typedef __attribute__((ext_vector_type(8))) __bf16 bf16x8;
typedef __attribute__((ext_vector_type(8))) unsigned short ushort8;
typedef __attribute__((ext_vector_type(4))) unsigned short ushort4v;
typedef __attribute__((ext_vector_type(4))) float  f32x4;

__device__ __forceinline__ float gelu_exact(float x) {
    return 0.5f * x * (1.0f + erff(x * 0.70710678118654752440f));
}

__device__ __forceinline__ unsigned short f2bf(float x) {
    __hip_bfloat16 h = __float2bfloat16(x);
    return *reinterpret_cast<unsigned short*>(&h);
}

__device__ __forceinline__ float bf2f(unsigned short u) {
    unsigned int v = ((unsigned int)u) << 16;
    return *reinterpret_cast<float*>(&v);
}

__device__ __forceinline__ void gload16(const void* g, void* l) {
    __builtin_amdgcn_global_load_lds(
        (const __attribute__((address_space(1))) void*)g,
        (__attribute__((address_space(3))) void*)l,
        16, 0, 0);
}

#define SB0() __builtin_amdgcn_sched_barrier(0)

// -------------------- f32 [K][N] -> bf16 [N][K] transpose-convert --------------------
__global__ void cvtT_kernel(const float* __restrict__ W, __hip_bfloat16* __restrict__ WT,
                            int K, int N) {
    __shared__ float tile[32][33];
    int k0 = blockIdx.y * 32, n0 = blockIdx.x * 32;
    int tx = threadIdx.x & 31, ty = threadIdx.x >> 5;   // 32x8
    #pragma unroll
    for (int i = 0; i < 32; i += 8)
        tile[ty + i][tx] = W[(long)(k0 + ty + i) * N + n0 + tx];
    __syncthreads();
    #pragma unroll
    for (int i = 0; i < 32; i += 8)
        WT[(long)(n0 + ty + i) * K + k0 + tx] = __float2bfloat16(tile[tx][ty + i]);
}

// -------------------- bias concat (bq|bk|bv -> bqkv) --------------------
__global__ void bias_concat_kernel(const float* __restrict__ bq,
                                   const float* __restrict__ bk,
                                   const float* __restrict__ bv,
                                   float* __restrict__ bqkv) {
    int i = blockIdx.x * 256 + threadIdx.x;   // 0..2303
    const float* src = (i < H_) ? bq : (i < 2 * H_) ? bk : bv;
    bqkv[i] = src[i % H_];
}

// ============ LayerNorm family: 192 threads, float4 (16B/lane) ============
__device__ __forceinline__ void ln_finish(float e0, float e1, float e2, float e3,
                                          int tid, float* tot1, float* tot2) {
    float s1 = e0 + e1 + e2 + e3;
    float s2 = e0 * e0 + e1 * e1 + e2 * e2 + e3 * e3;
    #pragma unroll
    for (int o = 32; o > 0; o >>= 1) { s1 += __shfl_xor(s1, o); s2 += __shfl_xor(s2, o); }
    __shared__ float ws1[3], ws2[3];
    int wid = tid >> 6;
    if ((tid & 63) == 0) { ws1[wid] = s1; ws2[wid] = s2; }
    __syncthreads();
    *tot1 = ws1[0] + ws1[1] + ws1[2];
    *tot2 = ws2[0] + ws2[1] + ws2[2];
}

__device__ __forceinline__ void ln_store(f32x4 e, float mean, float inv,
                                         const float* __restrict__ g,
                                         const float* __restrict__ bb,
                                         float* __restrict__ out,
                                         __hip_bfloat16* __restrict__ outb,
                                         long t, int tid) {
    f32x4 gv = reinterpret_cast<const f32x4*>(g)[tid];
    f32x4 bv = reinterpret_cast<const f32x4*>(bb)[tid];
    f32x4 r;
    #pragma unroll
    for (int i = 0; i < 4; ++i) r[i] = (e[i] - mean) * inv * gv[i] + bv[i];
    reinterpret_cast<f32x4*>(out + t * H_)[tid] = r;
    ushort4v u;
    #pragma unroll
    for (int i = 0; i < 4; ++i) u[i] = f2bf(r[i]);
    reinterpret_cast<ushort4v*>(reinterpret_cast<unsigned short*>(outb) + t * H_)[tid] = u;
}

// embeddings + LN
__global__ void embed_ln_kernel(const int* __restrict__ ids,
                                const float* __restrict__ Wword,
                                const float* __restrict__ Wpos,
                                const float* __restrict__ Wtype,
                                const float* __restrict__ g,
                                const float* __restrict__ b,
                                float* __restrict__ out,
                                __hip_bfloat16* __restrict__ outb) {
    long t = blockIdx.x;
    int s = (int)(t % S_);
    long id = ids[t];
    int tid = threadIdx.x;   // 0..191
    f32x4 e = reinterpret_cast<const f32x4*>(Wword + id * H_)[tid];
    f32x4 p = reinterpret_cast<const f32x4*>(Wpos + (long)s * H_)[tid];
    f32x4 y = reinterpret_cast<const f32x4*>(Wtype)[tid];
    #pragma unroll
    for (int i = 0; i < 4; ++i) e[i] += p[i] + y[i];
    float tot1, tot2;
    ln_finish(e[0], e[1], e[2], e[3], tid, &tot1, &tot2);
    float mean = tot1 * (1.0f / H_);
    float var  = tot2 * (1.0f / H_) - mean * mean;
    ln_store(e, mean, rsqrtf(var + 1e-12f), g, b, out, outb, t, tid);
}

// LN(a + p0 + p1), partials in bf16
__global__ void add_ln3_kernel(const float* __restrict__ a,
                               const __hip_bfloat16* __restrict__ p0,
                               const __hip_bfloat16* __restrict__ p1,
                               const float* __restrict__ g,
                               const float* __restrict__ bb,
                               float* __restrict__ out,
                               __hip_bfloat16* __restrict__ outb) {
    long t = blockIdx.x;
    int tid = threadIdx.x;
    long idx = t * (H_ / 4) + tid;
    f32x4 e = reinterpret_cast<const f32x4*>(a)[idx];
    ushort4v u = reinterpret_cast<const ushort4v*>(p0)[idx];
    ushort4v v = reinterpret_cast<const ushort4v*>(p1)[idx];
    #pragma unroll
    for (int i = 0; i < 4; ++i) e[i] += bf2f(u[i]) + bf2f(v[i]);
    float tot1, tot2;
    ln_finish(e[0], e[1], e[2], e[3], tid, &tot1, &tot2);
    float mean = tot1 * (1.0f / H_);
    float var  = tot2 * (1.0f / H_) - mean * mean;
    ln_store(e, mean, rsqrtf(var + 1e-12f), g, bb, out, outb, t, tid);
}

// LN(a + p0 + p1 + p2 + p3), partials in bf16
__global__ void add_ln5_kernel(const float* __restrict__ a,
                               const __hip_bfloat16* __restrict__ p0,
                               const __hip_bfloat16* __restrict__ p1,
                               const __hip_bfloat16* __restrict__ p2,
                               const __hip_bfloat16* __restrict__ p3,
                               const float* __restrict__ g,
                               const float* __restrict__ bb,
                               float* __restrict__ out,
                               __hip_bfloat16* __restrict__ outb) {
    long t = blockIdx.x;
    int tid = threadIdx.x;
    long idx = t * (H_ / 4) + tid;
    f32x4 e  = reinterpret_cast<const f32x4*>(a)[idx];
    ushort4v u0 = reinterpret_cast<const ushort4v*>(p0)[idx];
    ushort4v u1 = reinterpret_cast<const ushort4v*>(p1)[idx];
    ushort4v u2 = reinterpret_cast<const ushort4v*>(p2)[idx];
    ushort4v u3 = reinterpret_cast<const ushort4v*>(p3)[idx];
    #pragma unroll
    for (int i = 0; i < 4; ++i)
        e[i] += (bf2f(u0[i]) + bf2f(u1[i])) + (bf2f(u2[i]) + bf2f(u3[i]));
    float tot1, tot2;
    ln_finish(e[0], e[1], e[2], e[3], tid, &tot1, &tot2);
    float mean = tot1 * (1.0f / H_);
    float var  = tot2 * (1.0f / H_) - mean * mean;
    ln_store(e, mean, rsqrtf(var + 1e-12f), g, bb, out, outb, t, tid);
}

// ============ bf16 MFMA GEMM: 128x64 tiles, 1-barrier pipelined, XCD-swizzled ============
// T1: bijective XCD swizzle — work id wid = (bid%8)*(nwg/8) + bid/8 gives each XCD a
// contiguous chunk of tiles; consecutive work ids share the A row-band (x fastest) ->
// A panels become per-XCD L2-resident -> lower DMA latency (the measured per-step binder).
// All grids used have nwg % 8 == 0 (1152 / 1536 / 384).
template<int BM, int BN, int MI, int NJ, int ACT, int WF32, int WB16>
__global__ __launch_bounds__(256, 6) void mfma_gemm_kernel(
    const __hip_bfloat16* __restrict__ A,
    const __hip_bfloat16* __restrict__ BT,
    const float* __restrict__ bias,
    float* __restrict__ Cf,
    __hip_bfloat16* __restrict__ Cb,
    int M, int N, int Kc, int lda, int ldb) {
    constexpr int WC = BN / (NJ * 16);
    constexpr int WR = BM / (MI * 16);
    static_assert(WR * WC == 4, "4 waves");
    constexpr int LA = BM * 4 / 256;
    constexpr int LB = BN * 4 / 256;
    __shared__ __align__(16) __hip_bfloat16 sA[2][BM * 32];
    __shared__ __align__(16) __hip_bfloat16 sB[2][BN * 32];
    const int tid  = threadIdx.x;
    const int lane = tid & 63;
    const int w    = tid >> 6;
    const int wr   = w / WC, wc = w % WC;
    const int l15  = lane & 15, l4 = lane >> 4;

    // XCD-aware bijective swizzle (nwg divisible by 8)
    const int nwg = gridDim.x * gridDim.y;
    int bid = blockIdx.y * gridDim.x + blockIdx.x;
    const int cpx = nwg >> 3;
    const int wid = (bid & 7) * cpx + (bid >> 3);
    const int m0 = (wid / gridDim.x) * BM;
    const int n0 = (wid % gridDim.x) * BN;
    const int koff = blockIdx.z * Kc;
    const int goff = (l15 >> 1) & 3;

    auto stage = [&](int buf, int k0) {
        #pragma unroll
        for (int t = 0; t < LA; ++t) {
            int c = tid + 256 * t;
            int row = c >> 2, gq = c & 3;
            int gsrc = gq ^ ((row >> 1) & 3);
            gload16(A + (long)(m0 + row) * lda + koff + k0 + gsrc * 8, &sA[buf][row * 32 + gq * 8]);
        }
        #pragma unroll
        for (int t = 0; t < LB; ++t) {
            int c = tid + 256 * t;
            int row = c >> 2, gq = c & 3;
            int gsrc = gq ^ ((row >> 1) & 3);
            gload16(BT + (long)(n0 + row) * ldb + koff + k0 + gsrc * 8, &sB[buf][row * 32 + gq * 8]);
        }
    };

    f32x4 acc[MI][NJ] = {};
    const int nk = Kc >> 5;

    stage(0, 0);
    asm volatile("s_waitcnt vmcnt(0)" ::: "memory");
    SB0(); __builtin_amdgcn_s_barrier(); SB0();

    for (int t = 0; t < nk; ++t) {
        const int cur = t & 1;
        const bool more = (t + 1 < nk);
        if (more) stage(cur ^ 1, (t + 1) * 32);   // DMA drains under this step's compute

        const int gsw = (l4 ^ goff) * 8;
        bf16x8 af[MI], bf[NJ];
        #pragma unroll
        for (int i = 0; i < MI; ++i)
            af[i] = *reinterpret_cast<const bf16x8*>(&sA[cur][(wr * MI * 16 + i * 16 + l15) * 32 + gsw]);
        #pragma unroll
        for (int j = 0; j < NJ; ++j)
            bf[j] = *reinterpret_cast<const bf16x8*>(&sB[cur][(wc * NJ * 16 + j * 16 + l15) * 32 + gsw]);
        #pragma unroll
        for (int i = 0; i < MI; ++i)
            #pragma unroll
            for (int j = 0; j < NJ; ++j)
                acc[i][j] = __builtin_amdgcn_mfma_f32_16x16x32_bf16(af[i], bf[j], acc[i][j], 0, 0, 0);

        if (more) {
            SB0();
            asm volatile("s_waitcnt vmcnt(0)" ::: "memory");
            SB0(); __builtin_amdgcn_s_barrier(); SB0();
        }
    }

    float*          Cfz = Cf + (size_t)blockIdx.z * M * N;
    __hip_bfloat16* Cbz = Cb + (size_t)blockIdx.z * M * N;
    const bool addb = (blockIdx.z == 0);
    #pragma unroll
    for (int i = 0; i < MI; ++i) {
        #pragma unroll
        for (int j = 0; j < NJ; ++j) {
            int col = n0 + wc * NJ * 16 + j * 16 + l15;
            float bv = addb ? bias[col] : 0.f;
            #pragma unroll
            for (int r = 0; r < 4; ++r) {
                int row = m0 + wr * MI * 16 + i * 16 + l4 * 4 + r;
                float v = acc[i][j][r] + bv;
                if (ACT == 1) v = gelu_exact(v);
                if (WF32) Cfz[(long)row * N + col] = v;
                if (WB16) Cbz[(long)row * N + col] = __float2bfloat16(v);
            }
        }
    }
}

// -------------------- fused flash attention on fused QKV buffer (XCD-swizzled) --------------------
__global__ __launch_bounds__(256, 4) void flash_attn_kernel(
    const __hip_bfloat16* __restrict__ QKV,
    __hip_bfloat16* __restrict__ Ctx) {
    __shared__ __align__(16) unsigned short sK[64 * 72];
    __shared__ __align__(16) unsigned short sVt[64 * 72];
    __shared__ __align__(16) unsigned short sP[4 * 16 * 72];

    const int tid  = threadIdx.x;
    const int lane = tid & 63;
    const int w    = tid >> 6;
    const int l15  = lane & 15, l4 = lane >> 4;

    // T1 swizzle: consecutive work ids (same bh, different qb) share K/V -> same XCD chunk.
    const int nwg = gridDim.x * gridDim.y;   // 768
    int bid = blockIdx.y * gridDim.x + blockIdx.x;
    const int cpx = nwg >> 3;
    const int wid = (bid & 7) * cpx + (bid >> 3);
    const int qb = wid % gridDim.x;
    const int bh = wid / gridDim.x;
    const int b  = bh / NH_, hd = bh % NH_;
    const long rbase = (long)b * S_ * LDQ;
    const int qoff = hd * D_, koff = H_ + hd * D_, voff = 2 * H_ + hd * D_;

    const int qrow0 = qb * 64 + w * 16;
    bf16x8 af[2];
    #pragma unroll
    for (int ks = 0; ks < 2; ++ks)
        af[ks] = *reinterpret_cast<const bf16x8*>(
            QKV + rbase + (long)(qrow0 + l15) * LDQ + qoff + ks * 32 + l4 * 8);

    f32x4 ctx[4] = {};
    float m_run[4], l_run[4];
    #pragma unroll
    for (int r = 0; r < 4; ++r) { m_run[r] = -1e30f; l_run[r] = 0.f; }

    const int sr = tid >> 2;
    const int sc = (tid & 3) * 16;
    unsigned short* pl = sP + w * (16 * 72);

    for (int kv0 = 0; kv0 < S_; kv0 += 64) {
        const __hip_bfloat16* kg = QKV + rbase + (long)(kv0 + sr) * LDQ + koff + sc;
        const __hip_bfloat16* vg = QKV + rbase + (long)(kv0 + sr) * LDQ + voff + sc;
        ushort8 kv_a = *reinterpret_cast<const ushort8*>(kg);
        ushort8 kv_b = *reinterpret_cast<const ushort8*>(kg + 8);
        ushort8 vv_a = *reinterpret_cast<const ushort8*>(vg);
        ushort8 vv_b = *reinterpret_cast<const ushort8*>(vg + 8);
        __syncthreads();
        *reinterpret_cast<ushort8*>(sK + sr * 72 + sc)     = kv_a;
        *reinterpret_cast<ushort8*>(sK + sr * 72 + sc + 8) = kv_b;
        #pragma unroll
        for (int i = 0; i < 8; ++i) {
            sVt[(sc + i) * 72 + sr]     = vv_a[i];
            sVt[(sc + 8 + i) * 72 + sr] = vv_b[i];
        }
        __syncthreads();

        f32x4 s[4];
        __builtin_amdgcn_s_setprio(1);
        #pragma unroll
        for (int j = 0; j < 4; ++j) {
            s[j] = (f32x4){0.f, 0.f, 0.f, 0.f};
            #pragma unroll
            for (int ks = 0; ks < 2; ++ks) {
                bf16x8 bk = *reinterpret_cast<const bf16x8*>(sK + (j * 16 + l15) * 72 + ks * 32 + l4 * 8);
                s[j] = __builtin_amdgcn_mfma_f32_16x16x32_bf16(af[ks], bk, s[j], 0, 0, 0);
            }
        }
        __builtin_amdgcn_s_setprio(0);
        #pragma unroll
        for (int j = 0; j < 4; ++j) s[j] *= 0.125f;

        #pragma unroll
        for (int r = 0; r < 4; ++r) {
            float mx = fmaxf(fmaxf(s[0][r], s[1][r]), fmaxf(s[2][r], s[3][r]));
            #pragma unroll
            for (int o = 1; o < 16; o <<= 1) mx = fmaxf(mx, __shfl_xor(mx, o));
            float mnew = fmaxf(m_run[r], mx);
            float sum = 0.f;
            #pragma unroll
            for (int j = 0; j < 4; ++j) {
                float p = __expf(s[j][r] - mnew);
                s[j][r] = p; sum += p;
            }
            #pragma unroll
            for (int o = 1; o < 16; o <<= 1) sum += __shfl_xor(sum, o);
            float resc = __expf(m_run[r] - mnew);
            l_run[r] = l_run[r] * resc + sum;
            m_run[r] = mnew;
            #pragma unroll
            for (int j = 0; j < 4; ++j) ctx[j][r] *= resc;
        }

        #pragma unroll
        for (int j = 0; j < 4; ++j)
            #pragma unroll
            for (int r = 0; r < 4; ++r)
                pl[(l4 * 4 + r) * 72 + j * 16 + l15] = f2bf(s[j][r]);

        __builtin_amdgcn_s_setprio(1);
        #pragma unroll
        for (int ks = 0; ks < 2; ++ks) {
            bf16x8 ap = *reinterpret_cast<const bf16x8*>(pl + l15 * 72 + ks * 32 + l4 * 8);
            #pragma unroll
            for (int jd = 0; jd < 4; ++jd) {
                bf16x8 bv = *reinterpret_cast<const bf16x8*>(sVt + (jd * 16 + l15) * 72 + ks * 32 + l4 * 8);
                ctx[jd] = __builtin_amdgcn_mfma_f32_16x16x32_bf16(ap, bv, ctx[jd], 0, 0, 0);
            }
        }
        __builtin_amdgcn_s_setprio(0);
    }

    #pragma unroll
    for (int r = 0; r < 4; ++r) {
        float inv = 1.f / l_run[r];
        long tok = (long)b * S_ + qb * 64 + w * 16 + l4 * 4 + r;
        #pragma unroll
        for (int jd = 0; jd < 4; ++jd)
            Ctx[tok * H_ + hd * D_ + jd * 16 + l15] = __float2bfloat16(ctx[jd][r] * inv);
    }
}

// -------------------- pooled head v2: one wave per output column --------------------
__global__ void pooled2_kernel(const float* __restrict__ h,
                               const __hip_bfloat16* __restrict__ WpT,
                               const float* __restrict__ bp,
                               float* __restrict__ out) {
    const int col = blockIdx.x, b = blockIdx.y;
    const int lane = threadIdx.x;
    const float* hb = h + (long)b * S_ * H_;
    const __hip_bfloat16* wp = WpT + (long)col * H_;
    float acc = 0.f;
    #pragma unroll
    for (int i = 0; i < H_ / 64; ++i) {
        int k = lane + i * 64;
        acc += hb[k] * __bfloat162float(wp[k]);
    }
    #pragma unroll
    for (int o = 32; o > 0; o >>= 1) acc += __shfl_xor(acc, o);
    if (lane == 0) out[(long)b * H_ + col] = acc + bp[col];
}

extern "C" void kernel_launch(void* const* d_in, const int* in_sizes, int n_in,
                              void* d_out, int out_size, void* d_ws, size_t ws_size,
                              hipStream_t stream) {
    const int*   x      = (const int*)  d_in[0];
    const float* W_word = (const float*)d_in[1];
    const float* W_pos  = (const float*)d_in[2];
    const float* W_type = (const float*)d_in[3];
    const float* g_emb  = (const float*)d_in[4];
    const float* b_emb  = (const float*)d_in[5];
    const float* Wq     = (const float*)d_in[6];
    const float* bq     = (const float*)d_in[7];
    const float* Wk     = (const float*)d_in[8];
    const float* bk     = (const float*)d_in[9];
    const float* Wv     = (const float*)d_in[10];
    const float* bv     = (const float*)d_in[11];
    const float* Wo     = (const float*)d_in[12];
    const float* bo     = (const float*)d_in[13];
    const float* g_attn = (const float*)d_in[14];
    const float* b_attn = (const float*)d_in[15];
    const float* Wi     = (const float*)d_in[16];
    const float* bi     = (const float*)d_in[17];
    const float* Wd     = (const float*)d_in[18];
    const float* bd     = (const float*)d_in[19];
    const float* g_out  = (const float*)d_in[20];
    const float* b_out  = (const float*)d_in[21];
    const float* Wp     = (const float*)d_in[22];
    const float* bp     = (const float*)d_in[23];

    const size_t NT = (size_t)NTOK * H_;
    char* base = (char*)d_ws;
    size_t off = 0;
    auto alloc = [&](size_t bytes) -> char* {
        char* p = base + off;
        off += (bytes + 255) & ~(size_t)255;
        return p;
    };
    float* h    = (float*)alloc(NT * 4);
    float* xa   = (float*)alloc(NT * 4);
    __hip_bfloat16* kbb = (__hip_bfloat16*)alloc(NT * 2 * 4);   // bf16 split-K partials (4 planes)
    __hip_bfloat16* kbb1 = kbb + NT;
    __hip_bfloat16* kbb2 = kbb + 2 * NT;
    __hip_bfloat16* kbb3 = kbb + 3 * NT;
    __hip_bfloat16* h_b   = (__hip_bfloat16*)alloc(NT * 2);
    __hip_bfloat16* xa_b  = (__hip_bfloat16*)alloc(NT * 2);
    __hip_bfloat16* qkv_b = (__hip_bfloat16*)alloc((size_t)NTOK * LDQ * 2);
    __hip_bfloat16* ctx_b = (__hip_bfloat16*)alloc(NT * 2);
    __hip_bfloat16* ff1_b = (__hip_bfloat16*)alloc((size_t)NTOK * I_ * 2);
    __hip_bfloat16* WqkvT = (__hip_bfloat16*)alloc((size_t)LDQ * H_ * 2);
    __hip_bfloat16* WoT = (__hip_bfloat16*)alloc((size_t)H_ * H_ * 2);
    __hip_bfloat16* WiT = (__hip_bfloat16*)alloc((size_t)H_ * I_ * 2);
    __hip_bfloat16* WdT = (__hip_bfloat16*)alloc((size_t)I_ * H_ * 2);
    __hip_bfloat16* WpT = (__hip_bfloat16*)alloc((size_t)H_ * H_ * 2);
    float* bqkv = (float*)alloc(LDQ * 4);

    cvtT_kernel<<<dim3(H_/32, H_/32), 256, 0, stream>>>(Wq, WqkvT, H_, H_);
    cvtT_kernel<<<dim3(H_/32, H_/32), 256, 0, stream>>>(Wk, WqkvT + (size_t)H_ * H_, H_, H_);
    cvtT_kernel<<<dim3(H_/32, H_/32), 256, 0, stream>>>(Wv, WqkvT + (size_t)2 * H_ * H_, H_, H_);
    cvtT_kernel<<<dim3(H_/32, H_/32), 256, 0, stream>>>(Wo, WoT, H_, H_);
    cvtT_kernel<<<dim3(I_/32, H_/32), 256, 0, stream>>>(Wi, WiT, H_, I_);
    cvtT_kernel<<<dim3(H_/32, I_/32), 256, 0, stream>>>(Wd, WdT, I_, H_);
    cvtT_kernel<<<dim3(H_/32, H_/32), 256, 0, stream>>>(Wp, WpT, H_, H_);
    bias_concat_kernel<<<LDQ/256, 256, 0, stream>>>(bq, bk, bv, bqkv);

    embed_ln_kernel<<<NTOK, 192, 0, stream>>>(x, W_word, W_pos, W_type, g_emb, b_emb, h, h_b);

    float* hout = (float*)d_out;   // last layer writes d_out directly
    dim3 gqkv(LDQ/64, NTOK/128);         // (36, 32) = 1152 blocks (1152%8==0)
    dim3 gi(I_/64, NTOK/128);            // (48, 32) = 1536 blocks
    dim3 go(H_/64, NTOK/128, 2);         // (12, 32, 2): 384/plane
    dim3 gff2(H_/64, NTOK/128, 4);       // (12, 32, 4): 384/plane
    for (int layer = 0; layer < 6; ++layer) {
        mfma_gemm_kernel<128,64,4,2,0,0,1><<<gqkv, 256, 0, stream>>>(
            h_b, WqkvT, bqkv, nullptr, qkv_b, NTOK, LDQ, H_, H_, H_);
        flash_attn_kernel<<<dim3(S_/64, B_*NH_), 256, 0, stream>>>(qkv_b, ctx_b);
        mfma_gemm_kernel<128,64,4,2,0,0,1><<<go, 256, 0, stream>>>(
            ctx_b, WoT, bo, nullptr, kbb, NTOK, H_, H_/2, H_, H_);
        add_ln3_kernel<<<NTOK, 192, 0, stream>>>(h, kbb, kbb1, g_attn, b_attn, xa, xa_b);
        mfma_gemm_kernel<128,64,4,2,1,0,1><<<gi, 256, 0, stream>>>(
            xa_b, WiT, bi, nullptr, ff1_b, NTOK, I_, H_, H_, H_);
        mfma_gemm_kernel<128,64,4,2,0,0,1><<<gff2, 256, 0, stream>>>(
            ff1_b, WdT, bd, nullptr, kbb, NTOK, H_, I_/4, I_, I_);
        float* dst = (layer == 5) ? hout : h;
        add_ln5_kernel<<<NTOK, 192, 0, stream>>>(xa, kbb, kbb1, kbb2, kbb3,
                                                 g_out, b_out, dst, h_b);
    }

    pooled2_kernel<<<dim3(H_, B_), 64, 0, stream>>>(hout, WpT, bp, (float*)d_out + NT);
}

// Round 18
// 1071.405 us; speedup vs baseline: 1.0317x; 1.0020x over previous
//
#include <hip/hip_runtime.h>
#include <hip/hip_bf16.h>
#include <math.h>

#define B_  8
#define S_  512
#define H_  768
#define NH_ 12
#define D_  64
#define I_  3072
#define NTOK (B_*S_)   // 4096
#define LDQ 2304       // fused qkv row stride

typedef __attribute__((ext_vector_type(8))) __bf16 bf16x8;
typedef __attribute__((ext_vector_type(8))) unsigned short ushort8;
typedef __attribute__((ext_vector_type(4))) unsigned short ushort4v;
typedef __attribute__((ext_vector_type(4))) float  f32x4;

__device__ __forceinline__ float gelu_exact(float x) {
    return 0.5f * x * (1.0f + erff(x * 0.70710678118654752440f));
}

__device__ __forceinline__ unsigned short f2bf(float x) {
    __hip_bfloat16 h = __float2bfloat16(x);
    return *reinterpret_cast<unsigned short*>(&h);
}

__device__ __forceinline__ float bf2f(unsigned short u) {
    unsigned int v = ((unsigned int)u) << 16;
    return *reinterpret_cast<float*>(&v);
}

__device__ __forceinline__ void gload16(const void* g, void* l) {
    __builtin_amdgcn_global_load_lds(
        (const __attribute__((address_space(1))) void*)g,
        (__attribute__((address_space(3))) void*)l,
        16, 0, 0);
}

#define SB0() __builtin_amdgcn_sched_barrier(0)

// -------------------- f32 [K][N] -> bf16 [N][K] transpose-convert --------------------
__global__ void cvtT_kernel(const float* __restrict__ W, __hip_bfloat16* __restrict__ WT,
                            int K, int N) {
    __shared__ float tile[32][33];
    int k0 = blockIdx.y * 32, n0 = blockIdx.x * 32;
    int tx = threadIdx.x & 31, ty = threadIdx.x >> 5;   // 32x8
    #pragma unroll
    for (int i = 0; i < 32; i += 8)
        tile[ty + i][tx] = W[(long)(k0 + ty + i) * N + n0 + tx];
    __syncthreads();
    #pragma unroll
    for (int i = 0; i < 32; i += 8)
        WT[(long)(n0 + ty + i) * K + k0 + tx] = __float2bfloat16(tile[tx][ty + i]);
}

// -------------------- bias concat (bq|bk|bv -> bqkv) --------------------
__global__ void bias_concat_kernel(const float* __restrict__ bq,
                                   const float* __restrict__ bk,
                                   const float* __restrict__ bv,
                                   float* __restrict__ bqkv) {
    int i = blockIdx.x * 256 + threadIdx.x;   // 0..2303
    const float* src = (i < H_) ? bq : (i < 2 * H_) ? bk : bv;
    bqkv[i] = src[i % H_];
}

// ============ LayerNorm family: 192 threads, float4 (16B/lane) ============
__device__ __forceinline__ void ln_finish(float e0, float e1, float e2, float e3,
                                          int tid, float* tot1, float* tot2) {
    float s1 = e0 + e1 + e2 + e3;
    float s2 = e0 * e0 + e1 * e1 + e2 * e2 + e3 * e3;
    #pragma unroll
    for (int o = 32; o > 0; o >>= 1) { s1 += __shfl_xor(s1, o); s2 += __shfl_xor(s2, o); }
    __shared__ float ws1[3], ws2[3];
    int wid = tid >> 6;
    if ((tid & 63) == 0) { ws1[wid] = s1; ws2[wid] = s2; }
    __syncthreads();
    *tot1 = ws1[0] + ws1[1] + ws1[2];
    *tot2 = ws2[0] + ws2[1] + ws2[2];
}

__device__ __forceinline__ void ln_store(f32x4 e, float mean, float inv,
                                         const float* __restrict__ g,
                                         const float* __restrict__ bb,
                                         float* __restrict__ out,
                                         __hip_bfloat16* __restrict__ outb,
                                         long t, int tid) {
    f32x4 gv = reinterpret_cast<const f32x4*>(g)[tid];
    f32x4 bv = reinterpret_cast<const f32x4*>(bb)[tid];
    f32x4 r;
    #pragma unroll
    for (int i = 0; i < 4; ++i) r[i] = (e[i] - mean) * inv * gv[i] + bv[i];
    reinterpret_cast<f32x4*>(out + t * H_)[tid] = r;
    ushort4v u;
    #pragma unroll
    for (int i = 0; i < 4; ++i) u[i] = f2bf(r[i]);
    reinterpret_cast<ushort4v*>(reinterpret_cast<unsigned short*>(outb) + t * H_)[tid] = u;
}

// embeddings + LN
__global__ void embed_ln_kernel(const int* __restrict__ ids,
                                const float* __restrict__ Wword,
                                const float* __restrict__ Wpos,
                                const float* __restrict__ Wtype,
                                const float* __restrict__ g,
                                const float* __restrict__ b,
                                float* __restrict__ out,
                                __hip_bfloat16* __restrict__ outb) {
    long t = blockIdx.x;
    int s = (int)(t % S_);
    long id = ids[t];
    int tid = threadIdx.x;   // 0..191
    f32x4 e = reinterpret_cast<const f32x4*>(Wword + id * H_)[tid];
    f32x4 p = reinterpret_cast<const f32x4*>(Wpos + (long)s * H_)[tid];
    f32x4 y = reinterpret_cast<const f32x4*>(Wtype)[tid];
    #pragma unroll
    for (int i = 0; i < 4; ++i) e[i] += p[i] + y[i];
    float tot1, tot2;
    ln_finish(e[0], e[1], e[2], e[3], tid, &tot1, &tot2);
    float mean = tot1 * (1.0f / H_);
    float var  = tot2 * (1.0f / H_) - mean * mean;
    ln_store(e, mean, rsqrtf(var + 1e-12f), g, b, out, outb, t, tid);
}

// LN(a + p0 + p1), partials in bf16
__global__ void add_ln3_kernel(const float* __restrict__ a,
                               const __hip_bfloat16* __restrict__ p0,
                               const __hip_bfloat16* __restrict__ p1,
                               const float* __restrict__ g,
                               const float* __restrict__ bb,
                               float* __restrict__ out,
                               __hip_bfloat16* __restrict__ outb) {
    long t = blockIdx.x;
    int tid = threadIdx.x;
    long idx = t * (H_ / 4) + tid;
    f32x4 e = reinterpret_cast<const f32x4*>(a)[idx];
    ushort4v u = reinterpret_cast<const ushort4v*>(p0)[idx];
    ushort4v v = reinterpret_cast<const ushort4v*>(p1)[idx];
    #pragma unroll
    for (int i = 0; i < 4; ++i) e[i] += bf2f(u[i]) + bf2f(v[i]);
    float tot1, tot2;
    ln_finish(e[0], e[1], e[2], e[3], tid, &tot1, &tot2);
    float mean = tot1 * (1.0f / H_);
    float var  = tot2 * (1.0f / H_) - mean * mean;
    ln_store(e, mean, rsqrtf(var + 1e-12f), g, bb, out, outb, t, tid);
}

// LN(a + p0 + p1 + p2 + p3), partials in bf16
__global__ void add_ln5_kernel(const float* __restrict__ a,
                               const __hip_bfloat16* __restrict__ p0,
                               const __hip_bfloat16* __restrict__ p1,
                               const __hip_bfloat16* __restrict__ p2,
                               const __hip_bfloat16* __restrict__ p3,
                               const float* __restrict__ g,
                               const float* __restrict__ bb,
                               float* __restrict__ out,
                               __hip_bfloat16* __restrict__ outb) {
    long t = blockIdx.x;
    int tid = threadIdx.x;
    long idx = t * (H_ / 4) + tid;
    f32x4 e  = reinterpret_cast<const f32x4*>(a)[idx];
    ushort4v u0 = reinterpret_cast<const ushort4v*>(p0)[idx];
    ushort4v u1 = reinterpret_cast<const ushort4v*>(p1)[idx];
    ushort4v u2 = reinterpret_cast<const ushort4v*>(p2)[idx];
    ushort4v u3 = reinterpret_cast<const ushort4v*>(p3)[idx];
    #pragma unroll
    for (int i = 0; i < 4; ++i)
        e[i] += (bf2f(u0[i]) + bf2f(u1[i])) + (bf2f(u2[i]) + bf2f(u3[i]));
    float tot1, tot2;
    ln_finish(e[0], e[1], e[2], e[3], tid, &tot1, &tot2);
    float mean = tot1 * (1.0f / H_);
    float var  = tot2 * (1.0f / H_) - mean * mean;
    ln_store(e, mean, rsqrtf(var + 1e-12f), g, bb, out, outb, t, tid);
}

// ============ bf16 MFMA GEMM: 128x64 tiles, 1-barrier pipelined, XCD-swizzled, T5 setprio ============
template<int BM, int BN, int MI, int NJ, int ACT, int WF32, int WB16>
__global__ __launch_bounds__(256, 6) void mfma_gemm_kernel(
    const __hip_bfloat16* __restrict__ A,
    const __hip_bfloat16* __restrict__ BT,
    const float* __restrict__ bias,
    float* __restrict__ Cf,
    __hip_bfloat16* __restrict__ Cb,
    int M, int N, int Kc, int lda, int ldb) {
    constexpr int WC = BN / (NJ * 16);
    constexpr int WR = BM / (MI * 16);
    static_assert(WR * WC == 4, "4 waves");
    constexpr int LA = BM * 4 / 256;
    constexpr int LB = BN * 4 / 256;
    __shared__ __align__(16) __hip_bfloat16 sA[2][BM * 32];
    __shared__ __align__(16) __hip_bfloat16 sB[2][BN * 32];
    const int tid  = threadIdx.x;
    const int lane = tid & 63;
    const int w    = tid >> 6;
    const int wr   = w / WC, wc = w % WC;
    const int l15  = lane & 15, l4 = lane >> 4;

    // XCD-aware bijective swizzle (nwg divisible by 8)
    const int nwg = gridDim.x * gridDim.y;
    int bid = blockIdx.y * gridDim.x + blockIdx.x;
    const int cpx = nwg >> 3;
    const int wid = (bid & 7) * cpx + (bid >> 3);
    const int m0 = (wid / gridDim.x) * BM;
    const int n0 = (wid % gridDim.x) * BN;
    const int koff = blockIdx.z * Kc;
    const int goff = (l15 >> 1) & 3;

    auto stage = [&](int buf, int k0) {
        #pragma unroll
        for (int t = 0; t < LA; ++t) {
            int c = tid + 256 * t;
            int row = c >> 2, gq = c & 3;
            int gsrc = gq ^ ((row >> 1) & 3);
            gload16(A + (long)(m0 + row) * lda + koff + k0 + gsrc * 8, &sA[buf][row * 32 + gq * 8]);
        }
        #pragma unroll
        for (int t = 0; t < LB; ++t) {
            int c = tid + 256 * t;
            int row = c >> 2, gq = c & 3;
            int gsrc = gq ^ ((row >> 1) & 3);
            gload16(BT + (long)(n0 + row) * ldb + koff + k0 + gsrc * 8, &sB[buf][row * 32 + gq * 8]);
        }
    };

    f32x4 acc[MI][NJ] = {};
    const int nk = Kc >> 5;

    stage(0, 0);
    asm volatile("s_waitcnt vmcnt(0)" ::: "memory");
    SB0(); __builtin_amdgcn_s_barrier(); SB0();

    for (int t = 0; t < nk; ++t) {
        const int cur = t & 1;
        const bool more = (t + 1 < nk);
        if (more) stage(cur ^ 1, (t + 1) * 32);   // DMA drains under this step's compute

        const int gsw = (l4 ^ goff) * 8;
        bf16x8 af[MI], bf[NJ];
        #pragma unroll
        for (int i = 0; i < MI; ++i)
            af[i] = *reinterpret_cast<const bf16x8*>(&sA[cur][(wr * MI * 16 + i * 16 + l15) * 32 + gsw]);
        #pragma unroll
        for (int j = 0; j < NJ; ++j)
            bf[j] = *reinterpret_cast<const bf16x8*>(&sB[cur][(wc * NJ * 16 + j * 16 + l15) * 32 + gsw]);
        __builtin_amdgcn_s_setprio(1);   // T5: favor MFMA-entering waves on the CU scheduler
        #pragma unroll
        for (int i = 0; i < MI; ++i)
            #pragma unroll
            for (int j = 0; j < NJ; ++j)
                acc[i][j] = __builtin_amdgcn_mfma_f32_16x16x32_bf16(af[i], bf[j], acc[i][j], 0, 0, 0);
        __builtin_amdgcn_s_setprio(0);

        if (more) {
            SB0();
            asm volatile("s_waitcnt vmcnt(0)" ::: "memory");
            SB0(); __builtin_amdgcn_s_barrier(); SB0();
        }
    }

    float*          Cfz = Cf + (size_t)blockIdx.z * M * N;
    __hip_bfloat16* Cbz = Cb + (size_t)blockIdx.z * M * N;
    const bool addb = (blockIdx.z == 0);
    #pragma unroll
    for (int i = 0; i < MI; ++i) {
        #pragma unroll
        for (int j = 0; j < NJ; ++j) {
            int col = n0 + wc * NJ * 16 + j * 16 + l15;
            float bv = addb ? bias[col] : 0.f;
            #pragma unroll
            for (int r = 0; r < 4; ++r) {
                int row = m0 + wr * MI * 16 + i * 16 + l4 * 4 + r;
                float v = acc[i][j][r] + bv;
                if (ACT == 1) v = gelu_exact(v);
                if (WF32) Cfz[(long)row * N + col] = v;
                if (WB16) Cbz[(long)row * N + col] = __float2bfloat16(v);
            }
        }
    }
}

// -------------------- fused flash attention on fused QKV buffer (XCD-swizzled) --------------------
__global__ __launch_bounds__(256, 4) void flash_attn_kernel(
    const __hip_bfloat16* __restrict__ QKV,
    __hip_bfloat16* __restrict__ Ctx) {
    __shared__ __align__(16) unsigned short sK[64 * 72];
    __shared__ __align__(16) unsigned short sVt[64 * 72];
    __shared__ __align__(16) unsigned short sP[4 * 16 * 72];

    const int tid  = threadIdx.x;
    const int lane = tid & 63;
    const int w    = tid >> 6;
    const int l15  = lane & 15, l4 = lane >> 4;

    const int nwg = gridDim.x * gridDim.y;   // 768
    int bid = blockIdx.y * gridDim.x + blockIdx.x;
    const int cpx = nwg >> 3;
    const int wid = (bid & 7) * cpx + (bid >> 3);
    const int qb = wid % gridDim.x;
    const int bh = wid / gridDim.x;
    const int b  = bh / NH_, hd = bh % NH_;
    const long rbase = (long)b * S_ * LDQ;
    const int qoff = hd * D_, koff = H_ + hd * D_, voff = 2 * H_ + hd * D_;

    const int qrow0 = qb * 64 + w * 16;
    bf16x8 af[2];
    #pragma unroll
    for (int ks = 0; ks < 2; ++ks)
        af[ks] = *reinterpret_cast<const bf16x8*>(
            QKV + rbase + (long)(qrow0 + l15) * LDQ + qoff + ks * 32 + l4 * 8);

    f32x4 ctx[4] = {};
    float m_run[4], l_run[4];
    #pragma unroll
    for (int r = 0; r < 4; ++r) { m_run[r] = -1e30f; l_run[r] = 0.f; }

    const int sr = tid >> 2;
    const int sc = (tid & 3) * 16;
    unsigned short* pl = sP + w * (16 * 72);

    for (int kv0 = 0; kv0 < S_; kv0 += 64) {
        const __hip_bfloat16* kg = QKV + rbase + (long)(kv0 + sr) * LDQ + koff + sc;
        const __hip_bfloat16* vg = QKV + rbase + (long)(kv0 + sr) * LDQ + voff + sc;
        ushort8 kv_a = *reinterpret_cast<const ushort8*>(kg);
        ushort8 kv_b = *reinterpret_cast<const ushort8*>(kg + 8);
        ushort8 vv_a = *reinterpret_cast<const ushort8*>(vg);
        ushort8 vv_b = *reinterpret_cast<const ushort8*>(vg + 8);
        __syncthreads();
        *reinterpret_cast<ushort8*>(sK + sr * 72 + sc)     = kv_a;
        *reinterpret_cast<ushort8*>(sK + sr * 72 + sc + 8) = kv_b;
        #pragma unroll
        for (int i = 0; i < 8; ++i) {
            sVt[(sc + i) * 72 + sr]     = vv_a[i];
            sVt[(sc + 8 + i) * 72 + sr] = vv_b[i];
        }
        __syncthreads();

        f32x4 s[4];
        __builtin_amdgcn_s_setprio(1);
        #pragma unroll
        for (int j = 0; j < 4; ++j) {
            s[j] = (f32x4){0.f, 0.f, 0.f, 0.f};
            #pragma unroll
            for (int ks = 0; ks < 2; ++ks) {
                bf16x8 bk = *reinterpret_cast<const bf16x8*>(sK + (j * 16 + l15) * 72 + ks * 32 + l4 * 8);
                s[j] = __builtin_amdgcn_mfma_f32_16x16x32_bf16(af[ks], bk, s[j], 0, 0, 0);
            }
        }
        __builtin_amdgcn_s_setprio(0);
        #pragma unroll
        for (int j = 0; j < 4; ++j) s[j] *= 0.125f;

        #pragma unroll
        for (int r = 0; r < 4; ++r) {
            float mx = fmaxf(fmaxf(s[0][r], s[1][r]), fmaxf(s[2][r], s[3][r]));
            #pragma unroll
            for (int o = 1; o < 16; o <<= 1) mx = fmaxf(mx, __shfl_xor(mx, o));
            float mnew = fmaxf(m_run[r], mx);
            float sum = 0.f;
            #pragma unroll
            for (int j = 0; j < 4; ++j) {
                float p = __expf(s[j][r] - mnew);
                s[j][r] = p; sum += p;
            }
            #pragma unroll
            for (int o = 1; o < 16; o <<= 1) sum += __shfl_xor(sum, o);
            float resc = __expf(m_run[r] - mnew);
            l_run[r] = l_run[r] * resc + sum;
            m_run[r] = mnew;
            #pragma unroll
            for (int j = 0; j < 4; ++j) ctx[j][r] *= resc;
        }

        #pragma unroll
        for (int j = 0; j < 4; ++j)
            #pragma unroll
            for (int r = 0; r < 4; ++r)
                pl[(l4 * 4 + r) * 72 + j * 16 + l15] = f2bf(s[j][r]);

        __builtin_amdgcn_s_setprio(1);
        #pragma unroll
        for (int ks = 0; ks < 2; ++ks) {
            bf16x8 ap = *reinterpret_cast<const bf16x8*>(pl + l15 * 72 + ks * 32 + l4 * 8);
            #pragma unroll
            for (int jd = 0; jd < 4; ++jd) {
                bf16x8 bv = *reinterpret_cast<const bf16x8*>(sVt + (jd * 16 + l15) * 72 + ks * 32 + l4 * 8);
                ctx[jd] = __builtin_amdgcn_mfma_f32_16x16x32_bf16(ap, bv, ctx[jd], 0, 0, 0);
            }
        }
        __builtin_amdgcn_s_setprio(0);
    }

    #pragma unroll
    for (int r = 0; r < 4; ++r) {
        float inv = 1.f / l_run[r];
        long tok = (long)b * S_ + qb * 64 + w * 16 + l4 * 4 + r;
        #pragma unroll
        for (int jd = 0; jd < 4; ++jd)
            Ctx[tok * H_ + hd * D_ + jd * 16 + l15] = __float2bfloat16(ctx[jd][r] * inv);
    }
}

// -------------------- pooled head v2: one wave per output column --------------------
__global__ void pooled2_kernel(const float* __restrict__ h,
                               const __hip_bfloat16* __restrict__ WpT,
                               const float* __restrict__ bp,
                               float* __restrict__ out) {
    const int col = blockIdx.x, b = blockIdx.y;
    const int lane = threadIdx.x;
    const float* hb = h + (long)b * S_ * H_;
    const __hip_bfloat16* wp = WpT + (long)col * H_;
    float acc = 0.f;
    #pragma unroll
    for (int i = 0; i < H_ / 64; ++i) {
        int k = lane + i * 64;
        acc += hb[k] * __bfloat162float(wp[k]);
    }
    #pragma unroll
    for (int o = 32; o > 0; o >>= 1) acc += __shfl_xor(acc, o);
    if (lane == 0) out[(long)b * H_ + col] = acc + bp[col];
}

extern "C" void kernel_launch(void* const* d_in, const int* in_sizes, int n_in,
                              void* d_out, int out_size, void* d_ws, size_t ws_size,
                              hipStream_t stream) {
    const int*   x      = (const int*)  d_in[0];
    const float* W_word = (const float*)d_in[1];
    const float* W_pos  = (const float*)d_in[2];
    const float* W_type = (const float*)d_in[3];
    const float* g_emb  = (const float*)d_in[4];
    const float* b_emb  = (const float*)d_in[5];
    const float* Wq     = (const float*)d_in[6];
    const float* bq     = (const float*)d_in[7];
    const float* Wk     = (const float*)d_in[8];
    const float* bk     = (const float*)d_in[9];
    const float* Wv     = (const float*)d_in[10];
    const float* bv     = (const float*)d_in[11];
    const float* Wo     = (const float*)d_in[12];
    const float* bo     = (const float*)d_in[13];
    const float* g_attn = (const float*)d_in[14];
    const float* b_attn = (const float*)d_in[15];
    const float* Wi     = (const float*)d_in[16];
    const float* bi     = (const float*)d_in[17];
    const float* Wd     = (const float*)d_in[18];
    const float* bd     = (const float*)d_in[19];
    const float* g_out  = (const float*)d_in[20];
    const float* b_out  = (const float*)d_in[21];
    const float* Wp     = (const float*)d_in[22];
    const float* bp     = (const float*)d_in[23];

    const size_t NT = (size_t)NTOK * H_;
    char* base = (char*)d_ws;
    size_t off = 0;
    auto alloc = [&](size_t bytes) -> char* {
        char* p = base + off;
        off += (bytes + 255) & ~(size_t)255;
        return p;
    };
    float* h    = (float*)alloc(NT * 4);
    float* xa   = (float*)alloc(NT * 4);
    __hip_bfloat16* kbb = (__hip_bfloat16*)alloc(NT * 2 * 4);   // bf16 split-K partials (4 planes)
    __hip_bfloat16* kbb1 = kbb + NT;
    __hip_bfloat16* kbb2 = kbb + 2 * NT;
    __hip_bfloat16* kbb3 = kbb + 3 * NT;
    __hip_bfloat16* h_b   = (__hip_bfloat16*)alloc(NT * 2);
    __hip_bfloat16* xa_b  = (__hip_bfloat16*)alloc(NT * 2);
    __hip_bfloat16* qkv_b = (__hip_bfloat16*)alloc((size_t)NTOK * LDQ * 2);
    __hip_bfloat16* ctx_b = (__hip_bfloat16*)alloc(NT * 2);
    __hip_bfloat16* ff1_b = (__hip_bfloat16*)alloc((size_t)NTOK * I_ * 2);
    __hip_bfloat16* WqkvT = (__hip_bfloat16*)alloc((size_t)LDQ * H_ * 2);
    __hip_bfloat16* WoT = (__hip_bfloat16*)alloc((size_t)H_ * H_ * 2);
    __hip_bfloat16* WiT = (__hip_bfloat16*)alloc((size_t)H_ * I_ * 2);
    __hip_bfloat16* WdT = (__hip_bfloat16*)alloc((size_t)I_ * H_ * 2);
    __hip_bfloat16* WpT = (__hip_bfloat16*)alloc((size_t)H_ * H_ * 2);
    float* bqkv = (float*)alloc(LDQ * 4);

    cvtT_kernel<<<dim3(H_/32, H_/32), 256, 0, stream>>>(Wq, WqkvT, H_, H_);
    cvtT_kernel<<<dim3(H_/32, H_/32), 256, 0, stream>>>(Wk, WqkvT + (size_t)H_ * H_, H_, H_);
    cvtT_kernel<<<dim3(H_/32, H_/32), 256, 0, stream>>>(Wv, WqkvT + (size_t)2 * H_ * H_, H_, H_);
    cvtT_kernel<<<dim3(H_/32, H_/32), 256, 0, stream>>>(Wo, WoT, H_, H_);
    cvtT_kernel<<<dim3(I_/32, H_/32), 256, 0, stream>>>(Wi, WiT, H_, I_);
    cvtT_kernel<<<dim3(H_/32, I_/32), 256, 0, stream>>>(Wd, WdT, I_, H_);
    cvtT_kernel<<<dim3(H_/32, H_/32), 256, 0, stream>>>(Wp, WpT, H_, H_);
    bias_concat_kernel<<<LDQ/256, 256, 0, stream>>>(bq, bk, bv, bqkv);

    embed_ln_kernel<<<NTOK, 192, 0, stream>>>(x, W_word, W_pos, W_type, g_emb, b_emb, h, h_b);

    float* hout = (float*)d_out;   // last layer writes d_out directly
    dim3 gqkv(LDQ/64, NTOK/128);         // (36, 32) = 1152 blocks
    dim3 gi(I_/64, NTOK/128);            // (48, 32) = 1536 blocks
    dim3 go(H_/64, NTOK/128, 2);         // (12, 32, 2): 384/plane
    dim3 gff2(H_/64, NTOK/128, 4);       // (12, 32, 4): 384/plane
    for (int layer = 0; layer < 6; ++layer) {
        mfma_gemm_kernel<128,64,4,2,0,0,1><<<gqkv, 256, 0, stream>>>(
            h_b, WqkvT, bqkv, nullptr, qkv_b, NTOK, LDQ, H_, H_, H_);
        flash_attn_kernel<<<dim3(S_/64, B_*NH_), 256, 0, stream>>>(qkv_b, ctx_b);
        mfma_gemm_kernel<128,64,4,2,0,0,1><<<go, 256, 0, stream>>>(
            ctx_b, WoT, bo, nullptr, kbb, NTOK, H_, H_/2, H_, H_);
        add_ln3_kernel<<<NTOK, 192, 0, stream>>>(h, kbb, kbb1, g_attn, b_attn, xa, xa_b);
        mfma_gemm_kernel<128,64,4,2,1,0,1><<<gi, 256, 0, stream>>>(
            xa_b, WiT, bi, nullptr, ff1_b, NTOK, I_, H_, H_, H_);
        mfma_gemm_kernel<128,64,4,2,0,0,1><<<gff2, 256, 0, stream>>>(
            ff1_b, WdT, bd, nullptr, kbb, NTOK, H_, I_/4, I_, I_);
        float* dst = (layer == 5) ? hout : h;
        add_ln5_kernel<<<NTOK, 192, 0, stream>>>(xa, kbb, kbb1, kbb2, kbb3,
                                                 g_out, b_out, dst, h_b);
    }

    pooled2_kernel<<<dim3(H_, B_), 64, 0, stream>>>(hout, WpT, bp, (float*)d_out + NT);
}

// Round 19
// 1042.781 us; speedup vs baseline: 1.0600x; 1.0274x over previous
//
#include <hip/hip_runtime.h>
#include <hip/hip_bf16.h>
#include <math.h>

#define B_  8
#define S_  512
#define H_  768
#define NH_ 12
#define D_  64
#define I_  3072
#define NTOK (B_*S_)   // 4096
#define LDQ 2304       // fused qkv row stride

typedef __attribute__((ext_vector_type(8))) __bf16 bf16x8;
typedef __attribute__((ext_vector_type(8))) unsigned short ushort8;
typedef __attribute__((ext_vector_type(4))) unsigned short ushort4v;
typedef __attribute__((ext_vector_type(4))) float  f32x4;

__device__ __forceinline__ float gelu_exact(float x) {
    return 0.5f * x * (1.0f + erff(x * 0.70710678118654752440f));
}

__device__ __forceinline__ unsigned short f2bf(float x) {
    __hip_bfloat16 h = __float2bfloat16(x);
    return *reinterpret_cast<unsigned short*>(&h);
}

__device__ __forceinline__ float bf2f(unsigned short u) {
    unsigned int v = ((unsigned int)u) << 16;
    return *reinterpret_cast<float*>(&v);
}

__device__ __forceinline__ void gload16(const void* g, void* l) {
    __builtin_amdgcn_global_load_lds(
        (const __attribute__((address_space(1))) void*)g,
        (__attribute__((address_space(3))) void*)l,
        16, 0, 0);
}

#define SB0() __builtin_amdgcn_sched_barrier(0)

// -------------------- f32 [K][N] -> bf16 [N][K] transpose-convert --------------------
__global__ void cvtT_kernel(const float* __restrict__ W, __hip_bfloat16* __restrict__ WT,
                            int K, int N) {
    __shared__ float tile[32][33];
    int k0 = blockIdx.y * 32, n0 = blockIdx.x * 32;
    int tx = threadIdx.x & 31, ty = threadIdx.x >> 5;   // 32x8
    #pragma unroll
    for (int i = 0; i < 32; i += 8)
        tile[ty + i][tx] = W[(long)(k0 + ty + i) * N + n0 + tx];
    __syncthreads();
    #pragma unroll
    for (int i = 0; i < 32; i += 8)
        WT[(long)(n0 + ty + i) * K + k0 + tx] = __float2bfloat16(tile[tx][ty + i]);
}

// -------------------- bias concat (bq|bk|bv -> bqkv) --------------------
__global__ void bias_concat_kernel(const float* __restrict__ bq,
                                   const float* __restrict__ bk,
                                   const float* __restrict__ bv,
                                   float* __restrict__ bqkv) {
    int i = blockIdx.x * 256 + threadIdx.x;   // 0..2303
    const float* src = (i < H_) ? bq : (i < 2 * H_) ? bk : bv;
    bqkv[i] = src[i % H_];
}

// ============ LayerNorm family: 192 threads, float4/bf16x4 (vectorized) ============
__device__ __forceinline__ void ln_finish(float e0, float e1, float e2, float e3,
                                          int tid, float* tot1, float* tot2) {
    float s1 = e0 + e1 + e2 + e3;
    float s2 = e0 * e0 + e1 * e1 + e2 * e2 + e3 * e3;
    #pragma unroll
    for (int o = 32; o > 0; o >>= 1) { s1 += __shfl_xor(s1, o); s2 += __shfl_xor(s2, o); }
    __shared__ float ws1[3], ws2[3];
    int wid = tid >> 6;
    if ((tid & 63) == 0) { ws1[wid] = s1; ws2[wid] = s2; }
    __syncthreads();
    *tot1 = ws1[0] + ws1[1] + ws1[2];
    *tot2 = ws2[0] + ws2[1] + ws2[2];
}

// write bf16 shadow always; f32 only when WF32 (final layer -> d_out)
template<int WF32>
__device__ __forceinline__ void ln_store(f32x4 e, float mean, float inv,
                                         const float* __restrict__ g,
                                         const float* __restrict__ bb,
                                         float* __restrict__ out,
                                         __hip_bfloat16* __restrict__ outb,
                                         long t, int tid) {
    f32x4 gv = reinterpret_cast<const f32x4*>(g)[tid];
    f32x4 bv = reinterpret_cast<const f32x4*>(bb)[tid];
    f32x4 r;
    #pragma unroll
    for (int i = 0; i < 4; ++i) r[i] = (e[i] - mean) * inv * gv[i] + bv[i];
    if (WF32) reinterpret_cast<f32x4*>(out + t * H_)[tid] = r;
    ushort4v u;
    #pragma unroll
    for (int i = 0; i < 4; ++i) u[i] = f2bf(r[i]);
    reinterpret_cast<ushort4v*>(reinterpret_cast<unsigned short*>(outb) + t * H_)[tid] = u;
}

// embeddings + LN (bf16 out only)
__global__ void embed_ln_kernel(const int* __restrict__ ids,
                                const float* __restrict__ Wword,
                                const float* __restrict__ Wpos,
                                const float* __restrict__ Wtype,
                                const float* __restrict__ g,
                                const float* __restrict__ b,
                                __hip_bfloat16* __restrict__ outb) {
    long t = blockIdx.x;
    int s = (int)(t % S_);
    long id = ids[t];
    int tid = threadIdx.x;   // 0..191
    f32x4 e = reinterpret_cast<const f32x4*>(Wword + id * H_)[tid];
    f32x4 p = reinterpret_cast<const f32x4*>(Wpos + (long)s * H_)[tid];
    f32x4 y = reinterpret_cast<const f32x4*>(Wtype)[tid];
    #pragma unroll
    for (int i = 0; i < 4; ++i) e[i] += p[i] + y[i];
    float tot1, tot2;
    ln_finish(e[0], e[1], e[2], e[3], tid, &tot1, &tot2);
    float mean = tot1 * (1.0f / H_);
    float var  = tot2 * (1.0f / H_) - mean * mean;
    ln_store<0>(e, mean, rsqrtf(var + 1e-12f), g, b, nullptr, outb, t, tid);
}

// LN(a + p0 + p1), all bf16 in; bf16 out
__global__ void add_ln3_kernel(const __hip_bfloat16* __restrict__ a,
                               const __hip_bfloat16* __restrict__ p0,
                               const __hip_bfloat16* __restrict__ p1,
                               const float* __restrict__ g,
                               const float* __restrict__ bb,
                               __hip_bfloat16* __restrict__ outb) {
    long t = blockIdx.x;
    int tid = threadIdx.x;
    long idx = t * (H_ / 4) + tid;
    ushort4v av = reinterpret_cast<const ushort4v*>(a)[idx];
    ushort4v u = reinterpret_cast<const ushort4v*>(p0)[idx];
    ushort4v v = reinterpret_cast<const ushort4v*>(p1)[idx];
    f32x4 e;
    #pragma unroll
    for (int i = 0; i < 4; ++i) e[i] = bf2f(av[i]) + bf2f(u[i]) + bf2f(v[i]);
    float tot1, tot2;
    ln_finish(e[0], e[1], e[2], e[3], tid, &tot1, &tot2);
    float mean = tot1 * (1.0f / H_);
    float var  = tot2 * (1.0f / H_) - mean * mean;
    ln_store<0>(e, mean, rsqrtf(var + 1e-12f), g, bb, nullptr, outb, t, tid);
}

// LN(a + p0 + p1 + p2 + p3), all bf16 in; f32 out only when WF32 (final layer)
template<int WF32>
__global__ void add_ln5_kernel(const __hip_bfloat16* __restrict__ a,
                               const __hip_bfloat16* __restrict__ p0,
                               const __hip_bfloat16* __restrict__ p1,
                               const __hip_bfloat16* __restrict__ p2,
                               const __hip_bfloat16* __restrict__ p3,
                               const float* __restrict__ g,
                               const float* __restrict__ bb,
                               float* __restrict__ outf,
                               __hip_bfloat16* __restrict__ outb) {
    long t = blockIdx.x;
    int tid = threadIdx.x;
    long idx = t * (H_ / 4) + tid;
    ushort4v av = reinterpret_cast<const ushort4v*>(a)[idx];
    ushort4v u0 = reinterpret_cast<const ushort4v*>(p0)[idx];
    ushort4v u1 = reinterpret_cast<const ushort4v*>(p1)[idx];
    ushort4v u2 = reinterpret_cast<const ushort4v*>(p2)[idx];
    ushort4v u3 = reinterpret_cast<const ushort4v*>(p3)[idx];
    f32x4 e;
    #pragma unroll
    for (int i = 0; i < 4; ++i)
        e[i] = bf2f(av[i]) + (bf2f(u0[i]) + bf2f(u1[i])) + (bf2f(u2[i]) + bf2f(u3[i]));
    float tot1, tot2;
    ln_finish(e[0], e[1], e[2], e[3], tid, &tot1, &tot2);
    float mean = tot1 * (1.0f / H_);
    float var  = tot2 * (1.0f / H_) - mean * mean;
    ln_store<WF32>(e, mean, rsqrtf(var + 1e-12f), g, bb, outf, outb, t, tid);
}

// ============ bf16 MFMA GEMM: 128x64 tiles, 1-barrier pipelined, XCD-swizzled, T5 setprio ============
template<int BM, int BN, int MI, int NJ, int ACT, int WF32, int WB16>
__global__ __launch_bounds__(256, 6) void mfma_gemm_kernel(
    const __hip_bfloat16* __restrict__ A,
    const __hip_bfloat16* __restrict__ BT,
    const float* __restrict__ bias,
    float* __restrict__ Cf,
    __hip_bfloat16* __restrict__ Cb,
    int M, int N, int Kc, int lda, int ldb) {
    constexpr int WC = BN / (NJ * 16);
    constexpr int WR = BM / (MI * 16);
    static_assert(WR * WC == 4, "4 waves");
    constexpr int LA = BM * 4 / 256;
    constexpr int LB = BN * 4 / 256;
    __shared__ __align__(16) __hip_bfloat16 sA[2][BM * 32];
    __shared__ __align__(16) __hip_bfloat16 sB[2][BN * 32];
    const int tid  = threadIdx.x;
    const int lane = tid & 63;
    const int w    = tid >> 6;
    const int wr   = w / WC, wc = w % WC;
    const int l15  = lane & 15, l4 = lane >> 4;

    // XCD-aware bijective swizzle (nwg divisible by 8)
    const int nwg = gridDim.x * gridDim.y;
    int bid = blockIdx.y * gridDim.x + blockIdx.x;
    const int cpx = nwg >> 3;
    const int wid = (bid & 7) * cpx + (bid >> 3);
    const int m0 = (wid / gridDim.x) * BM;
    const int n0 = (wid % gridDim.x) * BN;
    const int koff = blockIdx.z * Kc;
    const int goff = (l15 >> 1) & 3;

    auto stage = [&](int buf, int k0) {
        #pragma unroll
        for (int t = 0; t < LA; ++t) {
            int c = tid + 256 * t;
            int row = c >> 2, gq = c & 3;
            int gsrc = gq ^ ((row >> 1) & 3);
            gload16(A + (long)(m0 + row) * lda + koff + k0 + gsrc * 8, &sA[buf][row * 32 + gq * 8]);
        }
        #pragma unroll
        for (int t = 0; t < LB; ++t) {
            int c = tid + 256 * t;
            int row = c >> 2, gq = c & 3;
            int gsrc = gq ^ ((row >> 1) & 3);
            gload16(BT + (long)(n0 + row) * ldb + koff + k0 + gsrc * 8, &sB[buf][row * 32 + gq * 8]);
        }
    };

    f32x4 acc[MI][NJ] = {};
    const int nk = Kc >> 5;

    stage(0, 0);
    asm volatile("s_waitcnt vmcnt(0)" ::: "memory");
    SB0(); __builtin_amdgcn_s_barrier(); SB0();

    for (int t = 0; t < nk; ++t) {
        const int cur = t & 1;
        const bool more = (t + 1 < nk);
        if (more) stage(cur ^ 1, (t + 1) * 32);   // DMA drains under this step's compute

        const int gsw = (l4 ^ goff) * 8;
        bf16x8 af[MI], bf[NJ];
        #pragma unroll
        for (int i = 0; i < MI; ++i)
            af[i] = *reinterpret_cast<const bf16x8*>(&sA[cur][(wr * MI * 16 + i * 16 + l15) * 32 + gsw]);
        #pragma unroll
        for (int j = 0; j < NJ; ++j)
            bf[j] = *reinterpret_cast<const bf16x8*>(&sB[cur][(wc * NJ * 16 + j * 16 + l15) * 32 + gsw]);
        __builtin_amdgcn_s_setprio(1);
        #pragma unroll
        for (int i = 0; i < MI; ++i)
            #pragma unroll
            for (int j = 0; j < NJ; ++j)
                acc[i][j] = __builtin_amdgcn_mfma_f32_16x16x32_bf16(af[i], bf[j], acc[i][j], 0, 0, 0);
        __builtin_amdgcn_s_setprio(0);

        if (more) {
            SB0();
            asm volatile("s_waitcnt vmcnt(0)" ::: "memory");
            SB0(); __builtin_amdgcn_s_barrier(); SB0();
        }
    }

    float*          Cfz = Cf + (size_t)blockIdx.z * M * N;
    __hip_bfloat16* Cbz = Cb + (size_t)blockIdx.z * M * N;
    const bool addb = (blockIdx.z == 0);
    #pragma unroll
    for (int i = 0; i < MI; ++i) {
        #pragma unroll
        for (int j = 0; j < NJ; ++j) {
            int col = n0 + wc * NJ * 16 + j * 16 + l15;
            float bv = addb ? bias[col] : 0.f;
            #pragma unroll
            for (int r = 0; r < 4; ++r) {
                int row = m0 + wr * MI * 16 + i * 16 + l4 * 4 + r;
                float v = acc[i][j][r] + bv;
                if (ACT == 1) v = gelu_exact(v);
                if (WF32) Cfz[(long)row * N + col] = v;
                if (WB16) Cbz[(long)row * N + col] = __float2bfloat16(v);
            }
        }
    }
}

// -------------------- fused flash attention on fused QKV buffer (XCD-swizzled) --------------------
__global__ __launch_bounds__(256, 4) void flash_attn_kernel(
    const __hip_bfloat16* __restrict__ QKV,
    __hip_bfloat16* __restrict__ Ctx) {
    __shared__ __align__(16) unsigned short sK[64 * 72];
    __shared__ __align__(16) unsigned short sVt[64 * 72];
    __shared__ __align__(16) unsigned short sP[4 * 16 * 72];

    const int tid  = threadIdx.x;
    const int lane = tid & 63;
    const int w    = tid >> 6;
    const int l15  = lane & 15, l4 = lane >> 4;

    const int nwg = gridDim.x * gridDim.y;   // 768
    int bid = blockIdx.y * gridDim.x + blockIdx.x;
    const int cpx = nwg >> 3;
    const int wid = (bid & 7) * cpx + (bid >> 3);
    const int qb = wid % gridDim.x;
    const int bh = wid / gridDim.x;
    const int b  = bh / NH_, hd = bh % NH_;
    const long rbase = (long)b * S_ * LDQ;
    const int qoff = hd * D_, koff = H_ + hd * D_, voff = 2 * H_ + hd * D_;

    const int qrow0 = qb * 64 + w * 16;
    bf16x8 af[2];
    #pragma unroll
    for (int ks = 0; ks < 2; ++ks)
        af[ks] = *reinterpret_cast<const bf16x8*>(
            QKV + rbase + (long)(qrow0 + l15) * LDQ + qoff + ks * 32 + l4 * 8);

    f32x4 ctx[4] = {};
    float m_run[4], l_run[4];
    #pragma unroll
    for (int r = 0; r < 4; ++r) { m_run[r] = -1e30f; l_run[r] = 0.f; }

    const int sr = tid >> 2;
    const int sc = (tid & 3) * 16;
    unsigned short* pl = sP + w * (16 * 72);

    for (int kv0 = 0; kv0 < S_; kv0 += 64) {
        const __hip_bfloat16* kg = QKV + rbase + (long)(kv0 + sr) * LDQ + koff + sc;
        const __hip_bfloat16* vg = QKV + rbase + (long)(kv0 + sr) * LDQ + voff + sc;
        ushort8 kv_a = *reinterpret_cast<const ushort8*>(kg);
        ushort8 kv_b = *reinterpret_cast<const ushort8*>(kg + 8);
        ushort8 vv_a = *reinterpret_cast<const ushort8*>(vg);
        ushort8 vv_b = *reinterpret_cast<const ushort8*>(vg + 8);
        __syncthreads();
        *reinterpret_cast<ushort8*>(sK + sr * 72 + sc)     = kv_a;
        *reinterpret_cast<ushort8*>(sK + sr * 72 + sc + 8) = kv_b;
        #pragma unroll
        for (int i = 0; i < 8; ++i) {
            sVt[(sc + i) * 72 + sr]     = vv_a[i];
            sVt[(sc + 8 + i) * 72 + sr] = vv_b[i];
        }
        __syncthreads();

        f32x4 s[4];
        __builtin_amdgcn_s_setprio(1);
        #pragma unroll
        for (int j = 0; j < 4; ++j) {
            s[j] = (f32x4){0.f, 0.f, 0.f, 0.f};
            #pragma unroll
            for (int ks = 0; ks < 2; ++ks) {
                bf16x8 bk = *reinterpret_cast<const bf16x8*>(sK + (j * 16 + l15) * 72 + ks * 32 + l4 * 8);
                s[j] = __builtin_amdgcn_mfma_f32_16x16x32_bf16(af[ks], bk, s[j], 0, 0, 0);
            }
        }
        __builtin_amdgcn_s_setprio(0);
        #pragma unroll
        for (int j = 0; j < 4; ++j) s[j] *= 0.125f;

        #pragma unroll
        for (int r = 0; r < 4; ++r) {
            float mx = fmaxf(fmaxf(s[0][r], s[1][r]), fmaxf(s[2][r], s[3][r]));
            #pragma unroll
            for (int o = 1; o < 16; o <<= 1) mx = fmaxf(mx, __shfl_xor(mx, o));
            float mnew = fmaxf(m_run[r], mx);
            float sum = 0.f;
            #pragma unroll
            for (int j = 0; j < 4; ++j) {
                float p = __expf(s[j][r] - mnew);
                s[j][r] = p; sum += p;
            }
            #pragma unroll
            for (int o = 1; o < 16; o <<= 1) sum += __shfl_xor(sum, o);
            float resc = __expf(m_run[r] - mnew);
            l_run[r] = l_run[r] * resc + sum;
            m_run[r] = mnew;
            #pragma unroll
            for (int j = 0; j < 4; ++j) ctx[j][r] *= resc;
        }

        #pragma unroll
        for (int j = 0; j < 4; ++j)
            #pragma unroll
            for (int r = 0; r < 4; ++r)
                pl[(l4 * 4 + r) * 72 + j * 16 + l15] = f2bf(s[j][r]);

        __builtin_amdgcn_s_setprio(1);
        #pragma unroll
        for (int ks = 0; ks < 2; ++ks) {
            bf16x8 ap = *reinterpret_cast<const bf16x8*>(pl + l15 * 72 + ks * 32 + l4 * 8);
            #pragma unroll
            for (int jd = 0; jd < 4; ++jd) {
                bf16x8 bv = *reinterpret_cast<const bf16x8*>(sVt + (jd * 16 + l15) * 72 + ks * 32 + l4 * 8);
                ctx[jd] = __builtin_amdgcn_mfma_f32_16x16x32_bf16(ap, bv, ctx[jd], 0, 0, 0);
            }
        }
        __builtin_amdgcn_s_setprio(0);
    }

    #pragma unroll
    for (int r = 0; r < 4; ++r) {
        float inv = 1.f / l_run[r];
        long tok = (long)b * S_ + qb * 64 + w * 16 + l4 * 4 + r;
        #pragma unroll
        for (int jd = 0; jd < 4; ++jd)
            Ctx[tok * H_ + hd * D_ + jd * 16 + l15] = __float2bfloat16(ctx[jd][r] * inv);
    }
}

// -------------------- pooled head v2: one wave per output column --------------------
__global__ void pooled2_kernel(const float* __restrict__ h,
                               const __hip_bfloat16* __restrict__ WpT,
                               const float* __restrict__ bp,
                               float* __restrict__ out) {
    const int col = blockIdx.x, b = blockIdx.y;
    const int lane = threadIdx.x;
    const float* hb = h + (long)b * S_ * H_;
    const __hip_bfloat16* wp = WpT + (long)col * H_;
    float acc = 0.f;
    #pragma unroll
    for (int i = 0; i < H_ / 64; ++i) {
        int k = lane + i * 64;
        acc += hb[k] * __bfloat162float(wp[k]);
    }
    #pragma unroll
    for (int o = 32; o > 0; o >>= 1) acc += __shfl_xor(acc, o);
    if (lane == 0) out[(long)b * H_ + col] = acc + bp[col];
}

extern "C" void kernel_launch(void* const* d_in, const int* in_sizes, int n_in,
                              void* d_out, int out_size, void* d_ws, size_t ws_size,
                              hipStream_t stream) {
    const int*   x      = (const int*)  d_in[0];
    const float* W_word = (const float*)d_in[1];
    const float* W_pos  = (const float*)d_in[2];
    const float* W_type = (const float*)d_in[3];
    const float* g_emb  = (const float*)d_in[4];
    const float* b_emb  = (const float*)d_in[5];
    const float* Wq     = (const float*)d_in[6];
    const float* bq     = (const float*)d_in[7];
    const float* Wk     = (const float*)d_in[8];
    const float* bk     = (const float*)d_in[9];
    const float* Wv     = (const float*)d_in[10];
    const float* bv     = (const float*)d_in[11];
    const float* Wo     = (const float*)d_in[12];
    const float* bo     = (const float*)d_in[13];
    const float* g_attn = (const float*)d_in[14];
    const float* b_attn = (const float*)d_in[15];
    const float* Wi     = (const float*)d_in[16];
    const float* bi     = (const float*)d_in[17];
    const float* Wd     = (const float*)d_in[18];
    const float* bd     = (const float*)d_in[19];
    const float* g_out  = (const float*)d_in[20];
    const float* b_out  = (const float*)d_in[21];
    const float* Wp     = (const float*)d_in[22];
    const float* bp     = (const float*)d_in[23];

    const size_t NT = (size_t)NTOK * H_;
    char* base = (char*)d_ws;
    size_t off = 0;
    auto alloc = [&](size_t bytes) -> char* {
        char* p = base + off;
        off += (bytes + 255) & ~(size_t)255;
        return p;
    };
    __hip_bfloat16* kbb = (__hip_bfloat16*)alloc(NT * 2 * 4);   // bf16 split-K partials (4 planes)
    __hip_bfloat16* kbb1 = kbb + NT;
    __hip_bfloat16* kbb2 = kbb + 2 * NT;
    __hip_bfloat16* kbb3 = kbb + 3 * NT;
    __hip_bfloat16* h_b   = (__hip_bfloat16*)alloc(NT * 2);
    __hip_bfloat16* xa_b  = (__hip_bfloat16*)alloc(NT * 2);
    __hip_bfloat16* qkv_b = (__hip_bfloat16*)alloc((size_t)NTOK * LDQ * 2);
    __hip_bfloat16* ctx_b = (__hip_bfloat16*)alloc(NT * 2);
    __hip_bfloat16* ff1_b = (__hip_bfloat16*)alloc((size_t)NTOK * I_ * 2);
    __hip_bfloat16* WqkvT = (__hip_bfloat16*)alloc((size_t)LDQ * H_ * 2);
    __hip_bfloat16* WoT = (__hip_bfloat16*)alloc((size_t)H_ * H_ * 2);
    __hip_bfloat16* WiT = (__hip_bfloat16*)alloc((size_t)H_ * I_ * 2);
    __hip_bfloat16* WdT = (__hip_bfloat16*)alloc((size_t)I_ * H_ * 2);
    __hip_bfloat16* WpT = (__hip_bfloat16*)alloc((size_t)H_ * H_ * 2);
    float* bqkv = (float*)alloc(LDQ * 4);

    cvtT_kernel<<<dim3(H_/32, H_/32), 256, 0, stream>>>(Wq, WqkvT, H_, H_);
    cvtT_kernel<<<dim3(H_/32, H_/32), 256, 0, stream>>>(Wk, WqkvT + (size_t)H_ * H_, H_, H_);
    cvtT_kernel<<<dim3(H_/32, H_/32), 256, 0, stream>>>(Wv, WqkvT + (size_t)2 * H_ * H_, H_, H_);
    cvtT_kernel<<<dim3(H_/32, H_/32), 256, 0, stream>>>(Wo, WoT, H_, H_);
    cvtT_kernel<<<dim3(I_/32, H_/32), 256, 0, stream>>>(Wi, WiT, H_, I_);
    cvtT_kernel<<<dim3(H_/32, I_/32), 256, 0, stream>>>(Wd, WdT, I_, H_);
    cvtT_kernel<<<dim3(H_/32, H_/32), 256, 0, stream>>>(Wp, WpT, H_, H_);
    bias_concat_kernel<<<LDQ/256, 256, 0, stream>>>(bq, bk, bv, bqkv);

    embed_ln_kernel<<<NTOK, 192, 0, stream>>>(x, W_word, W_pos, W_type, g_emb, b_emb, h_b);

    float* hout = (float*)d_out;   // final layer writes f32 here for pooled head + output
    dim3 gqkv(LDQ/64, NTOK/128);         // (36, 32) = 1152 blocks
    dim3 gi(I_/64, NTOK/128);            // (48, 32) = 1536 blocks
    dim3 go(H_/64, NTOK/128, 2);         // (12, 32, 2): 384/plane
    dim3 gff2(H_/64, NTOK/128, 4);       // (12, 32, 4): 384/plane
    for (int layer = 0; layer < 6; ++layer) {
        mfma_gemm_kernel<128,64,4,2,0,0,1><<<gqkv, 256, 0, stream>>>(
            h_b, WqkvT, bqkv, nullptr, qkv_b, NTOK, LDQ, H_, H_, H_);
        flash_attn_kernel<<<dim3(S_/64, B_*NH_), 256, 0, stream>>>(qkv_b, ctx_b);
        mfma_gemm_kernel<128,64,4,2,0,0,1><<<go, 256, 0, stream>>>(
            ctx_b, WoT, bo, nullptr, kbb, NTOK, H_, H_/2, H_, H_);
        add_ln3_kernel<<<NTOK, 192, 0, stream>>>(h_b, kbb, kbb1, g_attn, b_attn, xa_b);
        mfma_gemm_kernel<128,64,4,2,1,0,1><<<gi, 256, 0, stream>>>(
            xa_b, WiT, bi, nullptr, ff1_b, NTOK, I_, H_, H_, H_);
        mfma_gemm_kernel<128,64,4,2,0,0,1><<<gff2, 256, 0, stream>>>(
            ff1_b, WdT, bd, nullptr, kbb, NTOK, H_, I_/4, I_, I_);
        if (layer == 5)
            add_ln5_kernel<1><<<NTOK, 192, 0, stream>>>(xa_b, kbb, kbb1, kbb2, kbb3,
                                                        g_out, b_out, hout, h_b);
        else
            add_ln5_kernel<0><<<NTOK, 192, 0, stream>>>(xa_b, kbb, kbb1, kbb2, kbb3,
                                                        g_out, b_out, nullptr, h_b);
    }

    pooled2_kernel<<<dim3(H_, B_), 64, 0, stream>>>(hout, WpT, bp, (float*)d_out + NT);
}